// Round 15
// baseline (324.780 us; speedup 1.0000x reference)
//
#include <hip/hip_runtime.h>
#include <math.h>

#define F_IN 128
#define HID 64
#define NLAYER 3
#define QSW 832     // fused gemm output cols: q(256)|k(256)|v(256)|skip(64)
#define QS_ROW 320  // qs row: q(256)|skip(64) bf16
#define KV_ROW 512  // kv row: 32 chunks x (8B K | 8B V) fp8, interleaved

typedef unsigned short ushort_t;
typedef __bf16 bf16x8 __attribute__((ext_vector_type(8)));
typedef unsigned short u16x8 __attribute__((ext_vector_type(8)));
typedef float f32x4 __attribute__((ext_vector_type(4)));
typedef float f32x2 __attribute__((ext_vector_type(2)));

__device__ __forceinline__ ushort_t f2bf(float f) {
  unsigned u = __float_as_uint(f);
  u += 0x7fffu + ((u >> 16) & 1u);  // RNE; inputs finite
  return (ushort_t)(u >> 16);
}
__device__ __forceinline__ float bf2f(ushort_t s) {
  return __uint_as_float(((unsigned)s) << 16);
}
__device__ __forceinline__ float blo(unsigned u) { return __uint_as_float(u << 16); }
__device__ __forceinline__ float bhi(unsigned u) { return __uint_as_float(u & 0xffff0000u); }

// decode 8 fp8(e4m3) bytes (one uint2) -> 4 x f32x2
__device__ __forceinline__ void dec8v(unsigned lo, unsigned hi, f32x2* f) {
  f[0] = __builtin_amdgcn_cvt_pk_f32_fp8((int)lo, false);
  f[1] = __builtin_amdgcn_cvt_pk_f32_fp8((int)lo, true);
  f[2] = __builtin_amdgcn_cvt_pk_f32_fp8((int)hi, false);
  f[3] = __builtin_amdgcn_cvt_pk_f32_fp8((int)hi, true);
}

// ---------------- fused aux kernel: weight pack | hist+rank | zero d_out ----------------
// Blocks [0, 105): weight packing (4 old pack-blocks per block, one per wave).
//   Pack blocks come FIRST so the latency-bound compose starts at t=0 and
//   overlaps the hist blocks that fill the rest of the machine.
// Blocks [105, 105+nbE): per-edge rank histogram.
// Blocks [105+nbE, ...): zero d_out.
__global__ __launch_bounds__(256) void aux_k(const int* __restrict__ dst, int* __restrict__ cnt,
                                             int* __restrict__ rank, int e, int nbE,
                                             const float* __restrict__ Wq, const float* __restrict__ Wk,
                                             const float* __restrict__ Wv, const float* __restrict__ Ws,
                                             const float* __restrict__ w0, const float* __restrict__ b0,
                                             const float* __restrict__ bq, const float* __restrict__ bk,
                                             const float* __restrict__ bv, const float* __restrict__ bs,
                                             ushort_t* __restrict__ wp0, ushort_t* __restrict__ wp12,
                                             float* __restrict__ bp,
                                             float* __restrict__ out, int out_size) {
  __shared__ float w0s[128 * 64];  // full lin0 weight, 32KB (compose blocks only)
  int blk = blockIdx.x;
  int t = threadIdx.x;
  if (blk < 105) {  // ---- weight packing: old block b = blk*4 + wave ----
    int b = blk * 4 + (t >> 6);
    int lane = t & 63;
    if (blk < 52) {  // layer-0 COMPOSE blocks: Wc = w0 @ [Wq|Wk|Wv|Ws]
      // cooperative stage of w0 into LDS (coalesced float4)
#pragma unroll
      for (int i = 0; i < 8; i++) {
        int idx = (t + i * 256) * 4;
        *(float4*)&w0s[idx] = *(const float4*)(w0 + idx);
      }
      __syncthreads();
      int ntg = b >> 2, kt = b & 3;
      int col = ntg * 16 + (lane & 15);
      int kb = kt * 32 + (lane >> 4) * 8;  // 0..127
      const float* W; int c, stride;
      if (col < 256)      { W = Wq; c = col;       stride = 256; }
      else if (col < 512) { W = Wk; c = col - 256; stride = 256; }
      else if (col < 768) { W = Wv; c = col - 512; stride = 256; }
      else                { W = Ws; c = col - 768; stride = 64; }
      float vals[8] = {0.f, 0.f, 0.f, 0.f, 0.f, 0.f, 0.f, 0.f};
#pragma unroll 4
      for (int j = 0; j < 64; j++) {
        float wj = W[(long long)j * stride + c];
#pragma unroll
        for (int ee = 0; ee < 8; ee++) vals[ee] = fmaf(w0s[(kb + ee) * 64 + j], wj, vals[ee]);
      }
      ushort_t* p = wp0 + ((long long)b * 64 + lane) * 8;
      ushort4 lo{f2bf(vals[0]), f2bf(vals[1]), f2bf(vals[2]), f2bf(vals[3])};
      ushort4 hi{f2bf(vals[4]), f2bf(vals[5]), f2bf(vals[6]), f2bf(vals[7])};
      *(ushort4*)p = lo;
      *(ushort4*)(p + 4) = hi;
    } else if (b < 416) {  // layers 1,2: plain fragment pack (pure copy)
      int idx = b - 208;
      int l = 1 + idx / 104, tt = idx % 104;
      int ntg = tt >> 1, kt = tt & 1;
      int col = ntg * 16 + (lane & 15);
      int kb = kt * 32 + (lane >> 4) * 8;
      const float* W; int c, stride;
      if (col < 256)      { W = Wq + (long long)l * 64 * 256; c = col;       stride = 256; }
      else if (col < 512) { W = Wk + (long long)l * 64 * 256; c = col - 256; stride = 256; }
      else if (col < 768) { W = Wv + (long long)l * 64 * 256; c = col - 512; stride = 256; }
      else                { W = Ws + (long long)l * 64 * 64;  c = col - 768; stride = 64; }
      float vals[8];
#pragma unroll
      for (int ee = 0; ee < 8; ee++) vals[ee] = W[(long long)(kb + ee) * stride + c];
      ushort_t* p = wp12 + (long long)(l - 1) * (104 * 512) + ((long long)tt * 64 + lane) * 8;
      ushort4 lo{f2bf(vals[0]), f2bf(vals[1]), f2bf(vals[2]), f2bf(vals[3])};
      ushort4 hi{f2bf(vals[4]), f2bf(vals[5]), f2bf(vals[6]), f2bf(vals[7])};
      *(ushort4*)p = lo;
      *(ushort4*)(p + 4) = hi;
    } else if (b < 419) {
      int l = b - 416;
      if (l == 0) {  // composed bias: bc = b0 @ W + b   (b0 via register shuffle)
        float b0v = b0[lane];
        for (int c = lane; c < QSW; c += 64) {
          const float* W; const float* borig; int cc, stride;
          if (c < 256)      { W = Wq; borig = bq; cc = c;       stride = 256; }
          else if (c < 512) { W = Wk; borig = bk; cc = c - 256; stride = 256; }
          else if (c < 768) { W = Wv; borig = bv; cc = c - 512; stride = 256; }
          else              { W = Ws; borig = bs; cc = c - 768; stride = 64; }
          float acc = borig[cc];
#pragma unroll 4
          for (int j = 0; j < 64; j++)
            acc = fmaf(__shfl(b0v, j), W[(long long)j * stride + cc], acc);
          bp[c] = acc;
        }
      } else {
        for (int c = lane; c < QSW; c += 64) {
          float v = (c < 256) ? bq[l * 256 + c]
                  : (c < 512) ? bk[l * 256 + c - 256]
                  : (c < 768) ? bv[l * 256 + c - 512]
                  : bs[l * 64 + c - 768];
          bp[l * QSW + c] = v;
        }
      }
    }
    return;
  }
  blk -= 105;
  if (blk < nbE) {  // ---- hist + rank ----
    int i = blk * 256 + t;
    if (i < e) rank[i] = atomicAdd(&cnt[dst[i]], 1);
    return;
  }
  blk -= nbE;  // ---- zero d_out ----
  int zi = blk * 256 + t;
  if (zi * 4 + 3 < out_size) {
    *(float4*)(out + zi * 4) = float4{0.f, 0.f, 0.f, 0.f};
  } else {
    for (int c = zi * 4; c < out_size; c++) out[c] = 0.f;
  }
}

// ---------------- block scan: wave-shfl based (2 barriers) ----------------
__global__ __launch_bounds__(1024) void scan_block_k(const int* __restrict__ cnt, int* __restrict__ excl,
                                                     int* __restrict__ bsum, int n) {
  __shared__ int wsum[16];
  int t = threadIdx.x;
  int wv = t >> 6, lane = t & 63;
  int i = blockIdx.x * 1024 + t;
  int orig = (i < n) ? cnt[i] : 0;
  int v = orig;
#pragma unroll
  for (int off = 1; off < 64; off <<= 1) {
    int u = __shfl_up(v, off);
    if (lane >= off) v += u;
  }
  if (lane == 63) wsum[wv] = v;
  __syncthreads();
  if (t < 16) {
    int s = wsum[t];
    int s2 = s;
#pragma unroll
    for (int off = 1; off < 16; off <<= 1) {
      int u = __shfl_up(s2, off);
      if (t >= off) s2 += u;
    }
    wsum[t] = s2 - s;  // exclusive prefix of wave sums
  }
  __syncthreads();
  int base = wsum[wv];
  if (i < n) excl[i] = base + v - orig;
  if (t == 1023) bsum[blockIdx.x] = base + v;
}

// ---------------- fused: bsum scan + rowp finalize + atomic-free scatter ----------------
__global__ __launch_bounds__(256) void scatter_rowptr_k(const int* __restrict__ src, const int* __restrict__ dst,
                                                        const int* __restrict__ excl, const int* __restrict__ bsum,
                                                        const int* __restrict__ rank, int* __restrict__ rowp,
                                                        int* __restrict__ srt, int n, int e, int nb) {
  __shared__ int sb[64];
  int t = threadIdx.x;
  if (t < 64) {  // wave 0: exclusive scan of <=64 block sums
    int orig = (t < nb) ? bsum[t] : 0;
    int v = orig;
#pragma unroll
    for (int off = 1; off < 64; off <<= 1) {
      int u = __shfl_up(v, off);
      if (t >= off) v += u;
    }
    sb[t] = v - orig;
  }
  __syncthreads();
  int i = blockIdx.x * 256 + t;
  if (i < n) rowp[i] = excl[i] + sb[i >> 10];
  if (i == 0) rowp[n] = e;
  if (i < e) {
    int d = dst[i];
    srt[excl[d] + sb[d >> 10] + rank[i]] = src[i];
  }
}

// ---------------- fused MFMA GEMM with LDS-staged coalesced epilogue ----------------
// Block = 32 rows x all 832 cols; 4 waves split the 52 col-tiles (13 each).
// LDS 37.9KB + VGPR ~104 -> 4 blocks/CU. MR=2 fragments/wave; depth-1 W
// prefetch in NAMED registers. K/V stored interleaved per 8-ch chunk.
#define QS_STR 328  // ushorts: 656B row stride
#define KV_STR 528  // bytes: 16B-aligned
template <int K, int AF32>
__global__ __launch_bounds__(256) void gemm_fused(const void* __restrict__ Av, const ushort_t* __restrict__ Wp,
                                                  const float* __restrict__ bias, ushort_t* __restrict__ Cq,
                                                  unsigned char* __restrict__ Ckv, int n) {
  constexpr int KT = K / 32;
  __shared__ ushort_t qs_lds[32][QS_STR];
  __shared__ unsigned char kv_lds[32][KV_STR];
  int tid = threadIdx.x;
  int lane = tid & 63;
  int wv = __builtin_amdgcn_readfirstlane((int)(tid >> 6));
  int m0 = blockIdx.x * 32;
  int lr = lane & 15, lq = lane >> 4;

  bf16x8 a[2][KT];
#pragma unroll
  for (int mr = 0; mr < 2; mr++) {
    int row = m0 + mr * 16 + lr;
    if (row >= n) row = n - 1;
    if constexpr (AF32) {
      const float* Af = (const float*)Av;
#pragma unroll
      for (int kt = 0; kt < KT; kt++) {
        const float* p = Af + (long long)row * K + kt * 32 + lq * 8;
        float4 f0 = *(const float4*)p;
        float4 f1 = *(const float4*)(p + 4);
        u16x8 u;
        u[0] = f2bf(f0.x); u[1] = f2bf(f0.y); u[2] = f2bf(f0.z); u[3] = f2bf(f0.w);
        u[4] = f2bf(f1.x); u[5] = f2bf(f1.y); u[6] = f2bf(f1.z); u[7] = f2bf(f1.w);
        a[mr][kt] = __builtin_bit_cast(bf16x8, u);
      }
    } else {
      const ushort_t* Ab = (const ushort_t*)Av;
#pragma unroll
      for (int kt = 0; kt < KT; kt++)
        a[mr][kt] = *(const bf16x8*)(Ab + (long long)row * K + kt * 32 + lq * 8);
    }
  }
  int ntg0 = wv * 13;
  bf16x8 bw[KT];   // current tile W-frags (named, compile-time indexed)
  bf16x8 bwn[KT];  // next tile
#pragma unroll
  for (int kt = 0; kt < KT; kt++)
    bw[kt] = *(const bf16x8*)(Wp + ((long long)(ntg0 * KT + kt) * 64 + lane) * 8);
  float4 b4 = *(const float4*)(bias + ntg0 * 16 + lq * 4);
#pragma unroll 1
  for (int t = 0; t < 13; t++) {
    int ntg = ntg0 + t;
    float4 b4n;
    if (t < 12) {  // prefetch next tile's W + bias into named regs
#pragma unroll
      for (int kt = 0; kt < KT; kt++)
        bwn[kt] = *(const bf16x8*)(Wp + ((long long)((ntg + 1) * KT + kt) * 64 + lane) * 8);
      b4n = *(const float4*)(bias + (ntg + 1) * 16 + lq * 4);
    }
    f32x4 acc0 = {b4.x, b4.y, b4.z, b4.w};
    f32x4 acc1 = acc0;
#pragma unroll
    for (int kt = 0; kt < KT; kt++) {
      acc0 = __builtin_amdgcn_mfma_f32_16x16x32_bf16(bw[kt], a[0][kt], acc0, 0, 0, 0);
      acc1 = __builtin_amdgcn_mfma_f32_16x16x32_bf16(bw[kt], a[1][kt], acc1, 0, 0, 0);
    }
    if (ntg < 16) {  // q -> bf16
      int c = ntg * 16 + lq * 4;
      ushort4 o0{f2bf(acc0[0]), f2bf(acc0[1]), f2bf(acc0[2]), f2bf(acc0[3])};
      ushort4 o1{f2bf(acc1[0]), f2bf(acc1[1]), f2bf(acc1[2]), f2bf(acc1[3])};
      *(ushort4*)&qs_lds[lr][c] = o0;
      *(ushort4*)&qs_lds[16 + lr][c] = o1;
    } else if (ntg < 48) {  // K/V -> fp8 e4m3, interleaved chunk layout
      bool isK = ntg < 32;
      int c = (isK ? (ntg - 16) : (ntg - 32)) * 16 + lq * 4;
      int pos = ((c >> 3) << 4) + (isK ? 0 : 8) + (c & 7);
      int p0 = __builtin_amdgcn_cvt_pk_fp8_f32(acc0[0], acc0[1], 0, false);
      p0 = __builtin_amdgcn_cvt_pk_fp8_f32(acc0[2], acc0[3], p0, true);
      int p1 = __builtin_amdgcn_cvt_pk_fp8_f32(acc1[0], acc1[1], 0, false);
      p1 = __builtin_amdgcn_cvt_pk_fp8_f32(acc1[2], acc1[3], p1, true);
      *(unsigned*)&kv_lds[lr][pos] = (unsigned)p0;
      *(unsigned*)&kv_lds[16 + lr][pos] = (unsigned)p1;
    } else {  // skip -> bf16 (qs cols 256..319)
      int c = 256 + (ntg - 48) * 16 + lq * 4;
      ushort4 o0{f2bf(acc0[0]), f2bf(acc0[1]), f2bf(acc0[2]), f2bf(acc0[3])};
      ushort4 o1{f2bf(acc1[0]), f2bf(acc1[1]), f2bf(acc1[2]), f2bf(acc1[3])};
      *(ushort4*)&qs_lds[lr][c] = o0;
      *(ushort4*)&qs_lds[16 + lr][c] = o1;
    }
#pragma unroll
    for (int kt = 0; kt < KT; kt++) bw[kt] = bwn[kt];
    b4 = b4n;
  }
  __syncthreads();
  int rows_here = n - m0;
  if (rows_here > 32) rows_here = 32;
  // qs out: rows are 640B dense -> contiguous 20KB per full block
  const char* qsl = (const char*)qs_lds;
  char* qout = (char*)Cq + (long long)m0 * (QS_ROW * 2);
#pragma unroll 1
  for (int off = tid * 16; off < 32 * 640; off += 4096) {
    int row = off / 640;
    if (row >= rows_here) break;
    int col = off - row * 640;
    uint4 v = *(const uint4*)(qsl + row * (QS_STR * 2) + col);
    *(uint4*)(qout + off) = v;
  }
  // kv out: rows 512B dense -> contiguous 16KB per full block
  const char* kvl = (const char*)kv_lds;
  char* kout = (char*)Ckv + (long long)m0 * KV_ROW;
#pragma unroll 1
  for (int off = tid * 16; off < 32 * 512; off += 4096) {
    int row = off >> 9;
    if (row >= rows_here) break;
    int col = off & 511;
    uint4 v = *(const uint4*)(kvl + row * KV_STR + col);
    *(uint4*)(kout + off) = v;
  }
}

// ---------------- fused attention + head-mean + skip + relu ----------------
// 1 node/wave. lane = half*32 + sl; chunk sl holds K[8ch]|V[8ch] in one 16B load.
// Per iteration: 8 edges (4 per half), packed f32x2 math, defer-max softmax.
__global__ __launch_bounds__(256) void attn_k(const ushort_t* __restrict__ qs,
                                              const unsigned char* __restrict__ kv,
                                              const int* __restrict__ rowp, const int* __restrict__ srt,
                                              ushort_t* __restrict__ hn, int n) {
  int wvv = __builtin_amdgcn_readfirstlane((int)(threadIdx.x >> 6));
  int node = blockIdx.x * 4 + wvv;
  if (node >= n) return;
  int lane = threadIdx.x & 63;
  int half = lane >> 5;
  int sl = lane & 31;
  const uint4 qu = *(const uint4*)(qs + (long long)node * QS_ROW + sl * 8);
  f32x2 qf[4];
  qf[0] = f32x2{blo(qu.x), bhi(qu.x)} * 0.125f;  // 1/sqrt(64) prescaled
  qf[1] = f32x2{blo(qu.y), bhi(qu.y)} * 0.125f;
  qf[2] = f32x2{blo(qu.z), bhi(qu.z)} * 0.125f;
  qf[3] = f32x2{blo(qu.w), bhi(qu.w)} * 0.125f;
  int rs = rowp[node], re = rowp[node + 1];
  int last = re - 1;
  unsigned nm1 = (unsigned)(n - 1);
  float m = -INFINITY, d = 0.f;
  f32x2 a2[4];
#pragma unroll
  for (int j = 0; j < 4; j++) a2[j] = f32x2{0.f, 0.f};

  for (int i = rs; i < re; i += 8) {
    int b0 = i + half * 4;
    // value-clamped indices (srt has >=12B tail slack inside d_ws)
    unsigned i0 = min((unsigned)srt[b0], nm1);
    unsigned i1 = min((unsigned)srt[b0 + 1], nm1);
    unsigned i2 = min((unsigned)srt[b0 + 2], nm1);
    unsigned i3 = min((unsigned)srt[b0 + 3], nm1);
    uint4 u0 = *(const uint4*)(kv + (long long)i0 * KV_ROW + sl * 16);
    uint4 u1 = *(const uint4*)(kv + (long long)i1 * KV_ROW + sl * 16);
    uint4 u2 = *(const uint4*)(kv + (long long)i2 * KV_ROW + sl * 16);
    uint4 u3 = *(const uint4*)(kv + (long long)i3 * KV_ROW + sl * 16);
    f32x2 kf0[4], kf1[4], kf2[4], kf3[4];
    dec8v(u0.x, u0.y, kf0); dec8v(u1.x, u1.y, kf1);
    dec8v(u2.x, u2.y, kf2); dec8v(u3.x, u3.y, kf3);
    f32x2 s0 = qf[0] * kf0[0], s1 = qf[0] * kf1[0], s2 = qf[0] * kf2[0], s3 = qf[0] * kf3[0];
#pragma unroll
    for (int j = 1; j < 4; j++) {
      s0 = s0 + qf[j] * kf0[j];
      s1 = s1 + qf[j] * kf1[j];
      s2 = s2 + qf[j] * kf2[j];
      s3 = s3 + qf[j] * kf3[j];
    }
    float t0 = s0[0] + s0[1], t1 = s1[0] + s1[1], t2 = s2[0] + s2[1], t3 = s3[0] + s3[1];
    t0 += __shfl_xor(t0, 1); t1 += __shfl_xor(t1, 1); t2 += __shfl_xor(t2, 1); t3 += __shfl_xor(t3, 1);
    t0 += __shfl_xor(t0, 2); t1 += __shfl_xor(t1, 2); t2 += __shfl_xor(t2, 2); t3 += __shfl_xor(t3, 2);
    t0 += __shfl_xor(t0, 4); t1 += __shfl_xor(t1, 4); t2 += __shfl_xor(t2, 4); t3 += __shfl_xor(t3, 4);
    if (b0 > last) t0 = -INFINITY;
    if (b0 + 1 > last) t1 = -INFINITY;
    if (b0 + 2 > last) t2 = -INFINITY;
    if (b0 + 3 > last) t3 = -INFINITY;
    float lm = fmaxf(fmaxf(t0, t1), fmaxf(t2, t3));
    lm = fmaxf(lm, __shfl_xor(lm, 32));
    if (__any(lm > m + 8.f)) {  // defer-max: rescale only on significant growth
      float mn = fmaxf(m, lm);
      float co = __expf(m - mn);  // first iter: exp(-inf)=0
      d *= co;
#pragma unroll
      for (int j = 0; j < 4; j++) a2[j] = a2[j] * co;
      m = mn;
    }
    float p0e = __expf(t0 - m), p1e = __expf(t1 - m), p2e = __expf(t2 - m), p3e = __expf(t3 - m);
    d += (p0e + p1e) + (p2e + p3e);
    f32x2 vf0[4], vf1[4], vf2[4], vf3[4];
    dec8v(u0.z, u0.w, vf0); dec8v(u1.z, u1.w, vf1);
    dec8v(u2.z, u2.w, vf2); dec8v(u3.z, u3.w, vf3);
    f32x2 pe0 = {p0e, p0e}, pe1 = {p1e, p1e}, pe2 = {p2e, p2e}, pe3 = {p3e, p3e};
#pragma unroll
    for (int j = 0; j < 4; j++)
      a2[j] = a2[j] + (pe0 * vf0[j] + pe1 * vf1[j]) + (pe2 * vf2[j] + pe3 * vf3[j]);
  }
  // merge halves (same chunk at lane^32)
  d += __shfl_xor(d, 32);
  float a[8];
#pragma unroll
  for (int j = 0; j < 4; j++) {
    a[2 * j] = a2[j][0] + __shfl_xor(a2[j][0], 32);
    a[2 * j + 1] = a2[j][1] + __shfl_xor(a2[j][1], 32);
  }
  float inv = (d > 0.f) ? 1.f / d : 0.f;
  float r[8];
#pragma unroll
  for (int j = 0; j < 8; j++) {
    r[j] = a[j] * inv;
    r[j] += __shfl_xor(r[j], 8);   // head ^1
    r[j] += __shfl_xor(r[j], 16);  // head ^2
  }
  if (lane < 8) {
    const u16x8 s8 = *(const u16x8*)(qs + (long long)node * QS_ROW + 256 + lane * 8);
    u16x8 o;
#pragma unroll
    for (int j = 0; j < 8; j++)
      o[j] = f2bf(fmaxf(r[j] * 0.25f + bf2f(s8[j]), 0.f));
    *(u16x8*)(hn + (long long)node * HID + lane * 8) = o;
  }
}

// ---------------- global add pool (run-length; batch is sorted) ----------------
#define POOL_NPB 128
__global__ __launch_bounds__(64) void pool_k(const ushort_t* __restrict__ h, const int* __restrict__ batch,
                                             float* __restrict__ out, int n) {
  int c = threadIdx.x;
  int n0 = blockIdx.x * POOL_NPB;
  int n1 = n0 + POOL_NPB;
  if (n1 > n) n1 = n;
  if (n0 >= n) return;
  float acc = 0.f;
  int g = batch[n0];
  for (int node = n0; node < n1; node++) {
    int gb = batch[node];
    if (gb != g) {
      atomicAdd(&out[g * 64 + c], acc);
      acc = 0.f;
      g = gb;
    }
    acc += bf2f(h[(long long)node * 64 + c]);
  }
  atomicAdd(&out[g * 64 + c], acc);
}

extern "C" void kernel_launch(void* const* d_in, const int* in_sizes, int n_in,
                              void* d_out, int out_size, void* d_ws, size_t ws_size,
                              hipStream_t stream) {
  const float* x  = (const float*)d_in[0];
  const int* ei   = (const int*)d_in[1];
  const int* batch = (const int*)d_in[2];
  const float* w0 = (const float*)d_in[3];
  const float* b0 = (const float*)d_in[4];
  const float* Wq = (const float*)d_in[5];
  const float* bq = (const float*)d_in[6];
  const float* Wk = (const float*)d_in[7];
  const float* bk = (const float*)d_in[8];
  const float* Wv = (const float*)d_in[9];
  const float* bv = (const float*)d_in[10];
  const float* Ws = (const float*)d_in[11];
  const float* bs = (const float*)d_in[12];
  int N = in_sizes[0] / F_IN;
  int E = in_sizes[1] / 2;
  const int* esrc = ei;
  const int* edst = ei + E;

  // ---- workspace layout ----
  float* bp = (float*)d_ws;                                   // 3*832 f32
  unsigned char* kvb = (unsigned char*)(bp + 3 * QSW);        // N*512 fp8
  ushort_t* ha = (ushort_t*)(kvb + (size_t)N * KV_ROW);
  ushort_t* hb = ha + (long long)N * HID;
  ushort_t* qs = hb + (long long)N * HID;                     // N x 320 bf16
  ushort_t* wp0  = qs + (long long)N * QS_ROW;                // 208 * 512
  ushort_t* wp12 = wp0 + 208 * 512;                           // 2 * 104 * 512
  int* cnt  = (int*)(wp12 + 2 * 104 * 512);
  int* excl = cnt + N;
  int* rowp = excl + N;
  int* bsum = rowp + N + 1;
  int* rank = bsum + 64;                                      // E ints
  int* srt  = rank + E;                                       // E ints (+tail slack in ws)

  int nbE = (E + 255) / 256;
  int sbBlocks = (N + 1023) / 1024;
  int nzBlocks = (out_size / 4 + 255) / 256;

  // CSR by dst + weight pack + d_out zero (fused aux kernel; pack blocks first)
  hipMemsetAsync(cnt, 0, (size_t)N * sizeof(int), stream);
  aux_k<<<105 + nbE + nzBlocks, 256, 0, stream>>>(edst, cnt, rank, E, nbE,
                                                  Wq, Wk, Wv, Ws, w0, b0, bq, bk, bv, bs,
                                                  wp0, wp12, bp, (float*)d_out, out_size);
  scan_block_k<<<sbBlocks, 1024, 0, stream>>>(cnt, excl, bsum, N);
  scatter_rowptr_k<<<nbE, 256, 0, stream>>>(esrc, edst, excl, bsum, rank, rowp, srt, N, E, sbBlocks);

  int gBlocks = (N + 31) / 32;  // 1 block = 32 rows x 832 cols (LDS 37.9KB)

  // layer 0: composed weights, A = x fp32 direct (K=128)
  gemm_fused<128, 1><<<gBlocks, 256, 0, stream>>>(x, wp0, bp, qs, kvb, N);
  attn_k<<<(N + 3) / 4, 256, 0, stream>>>(qs, kvb, rowp, srt, ha, N);
  // layer 1
  gemm_fused<64, 0><<<gBlocks, 256, 0, stream>>>(ha, wp12, bp + QSW, qs, kvb, N);
  attn_k<<<(N + 3) / 4, 256, 0, stream>>>(qs, kvb, rowp, srt, hb, N);
  // layer 2
  gemm_fused<64, 0><<<gBlocks, 256, 0, stream>>>(hb, wp12 + 104 * 512, bp + 2 * QSW, qs, kvb, N);
  attn_k<<<(N + 3) / 4, 256, 0, stream>>>(qs, kvb, rowp, srt, ha, N);

  // pool (d_out zeroed by aux_k)
  pool_k<<<(N + POOL_NPB - 1) / POOL_NPB, 64, 0, stream>>>(ha, batch, (float*)d_out, N);
}

// Round 16
// 308.662 us; speedup vs baseline: 1.0522x; 1.0522x over previous
//
#include <hip/hip_runtime.h>
#include <math.h>

#define F_IN 128
#define HID 64
#define NLAYER 3
#define QSW 832     // fused gemm output cols: q(256)|k(256)|v(256)|skip(64)
#define QS_ROW 320  // qs row: q(256)|skip(64) bf16
#define KV_ROW 512  // kv row: 32 chunks x (8B K | 8B V) fp8, interleaved

typedef unsigned short ushort_t;
typedef __bf16 bf16x8 __attribute__((ext_vector_type(8)));
typedef unsigned short u16x8 __attribute__((ext_vector_type(8)));
typedef float f32x4 __attribute__((ext_vector_type(4)));
typedef float f32x2 __attribute__((ext_vector_type(2)));

__device__ __forceinline__ ushort_t f2bf(float f) {
  unsigned u = __float_as_uint(f);
  u += 0x7fffu + ((u >> 16) & 1u);  // RNE; inputs finite
  return (ushort_t)(u >> 16);
}
__device__ __forceinline__ float bf2f(ushort_t s) {
  return __uint_as_float(((unsigned)s) << 16);
}
__device__ __forceinline__ float blo(unsigned u) { return __uint_as_float(u << 16); }
__device__ __forceinline__ float bhi(unsigned u) { return __uint_as_float(u & 0xffff0000u); }

// decode 8 fp8(e4m3) bytes (one uint2) -> 4 x f32x2
__device__ __forceinline__ void dec8v(unsigned lo, unsigned hi, f32x2* f) {
  f[0] = __builtin_amdgcn_cvt_pk_f32_fp8((int)lo, false);
  f[1] = __builtin_amdgcn_cvt_pk_f32_fp8((int)lo, true);
  f[2] = __builtin_amdgcn_cvt_pk_f32_fp8((int)hi, false);
  f[3] = __builtin_amdgcn_cvt_pk_f32_fp8((int)hi, true);
}

// ---------------- CSR: hist + per-edge rank (standalone, full occupancy) ----------------
__global__ __launch_bounds__(256) void hist_rank_k(const int* __restrict__ dst, int* __restrict__ cnt,
                                                   int* __restrict__ rank, int e) {
  int i = blockIdx.x * 256 + threadIdx.x;
  if (i < e) rank[i] = atomicAdd(&cnt[dst[i]], 1);
}

// ---------------- block scan: wave-shfl based (2 barriers) ----------------
__global__ __launch_bounds__(1024) void scan_block_k(const int* __restrict__ cnt, int* __restrict__ excl,
                                                     int* __restrict__ bsum, int n) {
  __shared__ int wsum[16];
  int t = threadIdx.x;
  int wv = t >> 6, lane = t & 63;
  int i = blockIdx.x * 1024 + t;
  int orig = (i < n) ? cnt[i] : 0;
  int v = orig;
#pragma unroll
  for (int off = 1; off < 64; off <<= 1) {
    int u = __shfl_up(v, off);
    if (lane >= off) v += u;
  }
  if (lane == 63) wsum[wv] = v;
  __syncthreads();
  if (t < 16) {
    int s = wsum[t];
    int s2 = s;
#pragma unroll
    for (int off = 1; off < 16; off <<= 1) {
      int u = __shfl_up(s2, off);
      if (t >= off) s2 += u;
    }
    wsum[t] = s2 - s;  // exclusive prefix of wave sums
  }
  __syncthreads();
  int base = wsum[wv];
  if (i < n) excl[i] = base + v - orig;
  if (t == 1023) bsum[blockIdx.x] = base + v;
}

// ---------------- fused: bsum scan + rowp finalize + atomic-free scatter ----------------
__global__ __launch_bounds__(256) void scatter_rowptr_k(const int* __restrict__ src, const int* __restrict__ dst,
                                                        const int* __restrict__ excl, const int* __restrict__ bsum,
                                                        const int* __restrict__ rank, int* __restrict__ rowp,
                                                        int* __restrict__ srt, int n, int e, int nb) {
  __shared__ int sb[64];
  int t = threadIdx.x;
  if (t < 64) {  // wave 0: exclusive scan of <=64 block sums
    int orig = (t < nb) ? bsum[t] : 0;
    int v = orig;
#pragma unroll
    for (int off = 1; off < 64; off <<= 1) {
      int u = __shfl_up(v, off);
      if (t >= off) v += u;
    }
    sb[t] = v - orig;
  }
  __syncthreads();
  int i = blockIdx.x * 256 + t;
  if (i < n) rowp[i] = excl[i] + sb[i >> 10];
  if (i == 0) rowp[n] = e;
  if (i < e) {
    int d = dst[i];
    srt[excl[d] + sb[d >> 10] + rank[i]] = src[i];
  }
}

// ---------------- weight packing + lin0 composition (one pack-unit per block) ----------------
// Blocks 0..207: layer-0 COMPOSED tiles Wc = w0 @ [Wq|Wk|Wv|Ws]; 4 waves split
//   the 64-deep j-loop 16 each, partials reduced through LDS (4x shorter chain).
// Blocks 208..415: layers 1,2 plain tile copy (wave 0 only; trivial).
// Blocks 416..418: bias rows (wave 0; layer 0 composed via shfl broadcast).
__global__ __launch_bounds__(256) void pack2_k(const float* __restrict__ Wq, const float* __restrict__ Wk,
                                               const float* __restrict__ Wv, const float* __restrict__ Ws,
                                               const float* __restrict__ w0, const float* __restrict__ b0,
                                               const float* __restrict__ bq, const float* __restrict__ bk,
                                               const float* __restrict__ bv, const float* __restrict__ bs,
                                               ushort_t* __restrict__ wp0, ushort_t* __restrict__ wp12,
                                               float* __restrict__ bp) {
  __shared__ float w0s[32 * 64];      // 8KB: w0 rows [kt*32, kt*32+32)
  __shared__ float part[3][64][8];    // 6KB: partial sums from waves 1..3
  int b = blockIdx.x;
  int t = threadIdx.x;
  int wv = t >> 6, lane = t & 63;
  if (b < 208) {  // ---- layer-0 compose ----
    int ntg = b >> 2, kt = b & 3;
    {  // stage w0 rows kt*32..+32 (2048 floats, coalesced)
      int base = kt * 32 * 64;
      int idx = t * 8;
      *(float4*)&w0s[idx] = *(const float4*)(w0 + base + idx);
      *(float4*)&w0s[idx + 4] = *(const float4*)(w0 + base + idx + 4);
    }
    __syncthreads();
    int col = ntg * 16 + (lane & 15);
    int kbl = (lane >> 4) * 8;  // local row base within the staged 32 rows
    const float* W; int c, stride;
    if (col < 256)      { W = Wq; c = col;       stride = 256; }
    else if (col < 512) { W = Wk; c = col - 256; stride = 256; }
    else if (col < 768) { W = Wv; c = col - 512; stride = 256; }
    else                { W = Ws; c = col - 768; stride = 64; }
    float vals[8] = {0.f, 0.f, 0.f, 0.f, 0.f, 0.f, 0.f, 0.f};
#pragma unroll 4
    for (int jj = 0; jj < 16; jj++) {
      int j = wv * 16 + jj;
      float wj = W[(long long)j * stride + c];
#pragma unroll
      for (int ee = 0; ee < 8; ee++) vals[ee] = fmaf(w0s[(kbl + ee) * 64 + j], wj, vals[ee]);
    }
    if (wv > 0) {
#pragma unroll
      for (int ee = 0; ee < 8; ee++) part[wv - 1][lane][ee] = vals[ee];
    }
    __syncthreads();
    if (wv == 0) {
#pragma unroll
      for (int ee = 0; ee < 8; ee++)
        vals[ee] += part[0][lane][ee] + part[1][lane][ee] + part[2][lane][ee];
      ushort_t* p = wp0 + ((long long)b * 64 + lane) * 8;
      ushort4 lo{f2bf(vals[0]), f2bf(vals[1]), f2bf(vals[2]), f2bf(vals[3])};
      ushort4 hi{f2bf(vals[4]), f2bf(vals[5]), f2bf(vals[6]), f2bf(vals[7])};
      *(ushort4*)p = lo;
      *(ushort4*)(p + 4) = hi;
    }
  } else if (b < 416) {  // ---- layers 1,2 plain pack (wave 0) ----
    if (wv != 0) return;
    int idx = b - 208;
    int l = 1 + idx / 104, tt = idx % 104;
    int ntg = tt >> 1, kt = tt & 1;
    int col = ntg * 16 + (lane & 15);
    int kb = kt * 32 + (lane >> 4) * 8;
    const float* W; int c, stride;
    if (col < 256)      { W = Wq + (long long)l * 64 * 256; c = col;       stride = 256; }
    else if (col < 512) { W = Wk + (long long)l * 64 * 256; c = col - 256; stride = 256; }
    else if (col < 768) { W = Wv + (long long)l * 64 * 256; c = col - 512; stride = 256; }
    else                { W = Ws + (long long)l * 64 * 64;  c = col - 768; stride = 64; }
    float vals[8];
#pragma unroll
    for (int ee = 0; ee < 8; ee++) vals[ee] = W[(long long)(kb + ee) * stride + c];
    ushort_t* p = wp12 + (long long)(l - 1) * (104 * 512) + ((long long)tt * 64 + lane) * 8;
    ushort4 lo{f2bf(vals[0]), f2bf(vals[1]), f2bf(vals[2]), f2bf(vals[3])};
    ushort4 hi{f2bf(vals[4]), f2bf(vals[5]), f2bf(vals[6]), f2bf(vals[7])};
    *(ushort4*)p = lo;
    *(ushort4*)(p + 4) = hi;
  } else {  // ---- bias rows (wave 0) ----
    if (wv != 0) return;
    int l = b - 416;
    if (l == 0) {  // composed bias: bc = b0 @ W + b (b0 via register shuffle)
      float b0v = b0[lane];
      for (int c = lane; c < QSW; c += 64) {
        const float* W; const float* borig; int cc, stride;
        if (c < 256)      { W = Wq; borig = bq; cc = c;       stride = 256; }
        else if (c < 512) { W = Wk; borig = bk; cc = c - 256; stride = 256; }
        else if (c < 768) { W = Wv; borig = bv; cc = c - 512; stride = 256; }
        else              { W = Ws; borig = bs; cc = c - 768; stride = 64; }
        float acc = borig[cc];
#pragma unroll 4
        for (int j = 0; j < 64; j++)
          acc = fmaf(__shfl(b0v, j), W[(long long)j * stride + cc], acc);
        bp[c] = acc;
      }
    } else {
      for (int c = lane; c < QSW; c += 64) {
        float v = (c < 256) ? bq[l * 256 + c]
                : (c < 512) ? bk[l * 256 + c - 256]
                : (c < 768) ? bv[l * 256 + c - 512]
                : bs[l * 64 + c - 768];
        bp[l * QSW + c] = v;
      }
    }
  }
}

// ---------------- fused MFMA GEMM with LDS-staged coalesced epilogue ----------------
// Block = 32 rows x all 832 cols; 4 waves split the 52 col-tiles (13 each).
// LDS 37.9KB + VGPR ~104 -> 4 blocks/CU. MR=2 fragments/wave; depth-1 W
// prefetch in NAMED registers. K/V stored interleaved per 8-ch chunk.
#define QS_STR 328  // ushorts: 656B row stride
#define KV_STR 528  // bytes: 16B-aligned
template <int K, int AF32>
__global__ __launch_bounds__(256) void gemm_fused(const void* __restrict__ Av, const ushort_t* __restrict__ Wp,
                                                  const float* __restrict__ bias, ushort_t* __restrict__ Cq,
                                                  unsigned char* __restrict__ Ckv, int n) {
  constexpr int KT = K / 32;
  __shared__ ushort_t qs_lds[32][QS_STR];
  __shared__ unsigned char kv_lds[32][KV_STR];
  int tid = threadIdx.x;
  int lane = tid & 63;
  int wv = __builtin_amdgcn_readfirstlane((int)(tid >> 6));
  int m0 = blockIdx.x * 32;
  int lr = lane & 15, lq = lane >> 4;

  bf16x8 a[2][KT];
#pragma unroll
  for (int mr = 0; mr < 2; mr++) {
    int row = m0 + mr * 16 + lr;
    if (row >= n) row = n - 1;
    if constexpr (AF32) {
      const float* Af = (const float*)Av;
#pragma unroll
      for (int kt = 0; kt < KT; kt++) {
        const float* p = Af + (long long)row * K + kt * 32 + lq * 8;
        float4 f0 = *(const float4*)p;
        float4 f1 = *(const float4*)(p + 4);
        u16x8 u;
        u[0] = f2bf(f0.x); u[1] = f2bf(f0.y); u[2] = f2bf(f0.z); u[3] = f2bf(f0.w);
        u[4] = f2bf(f1.x); u[5] = f2bf(f1.y); u[6] = f2bf(f1.z); u[7] = f2bf(f1.w);
        a[mr][kt] = __builtin_bit_cast(bf16x8, u);
      }
    } else {
      const ushort_t* Ab = (const ushort_t*)Av;
#pragma unroll
      for (int kt = 0; kt < KT; kt++)
        a[mr][kt] = *(const bf16x8*)(Ab + (long long)row * K + kt * 32 + lq * 8);
    }
  }
  int ntg0 = wv * 13;
  bf16x8 bw[KT];   // current tile W-frags (named, compile-time indexed)
  bf16x8 bwn[KT];  // next tile
#pragma unroll
  for (int kt = 0; kt < KT; kt++)
    bw[kt] = *(const bf16x8*)(Wp + ((long long)(ntg0 * KT + kt) * 64 + lane) * 8);
  float4 b4 = *(const float4*)(bias + ntg0 * 16 + lq * 4);
#pragma unroll 1
  for (int t = 0; t < 13; t++) {
    int ntg = ntg0 + t;
    float4 b4n;
    if (t < 12) {  // prefetch next tile's W + bias into named regs
#pragma unroll
      for (int kt = 0; kt < KT; kt++)
        bwn[kt] = *(const bf16x8*)(Wp + ((long long)((ntg + 1) * KT + kt) * 64 + lane) * 8);
      b4n = *(const float4*)(bias + (ntg + 1) * 16 + lq * 4);
    }
    f32x4 acc0 = {b4.x, b4.y, b4.z, b4.w};
    f32x4 acc1 = acc0;
#pragma unroll
    for (int kt = 0; kt < KT; kt++) {
      acc0 = __builtin_amdgcn_mfma_f32_16x16x32_bf16(bw[kt], a[0][kt], acc0, 0, 0, 0);
      acc1 = __builtin_amdgcn_mfma_f32_16x16x32_bf16(bw[kt], a[1][kt], acc1, 0, 0, 0);
    }
    if (ntg < 16) {  // q -> bf16
      int c = ntg * 16 + lq * 4;
      ushort4 o0{f2bf(acc0[0]), f2bf(acc0[1]), f2bf(acc0[2]), f2bf(acc0[3])};
      ushort4 o1{f2bf(acc1[0]), f2bf(acc1[1]), f2bf(acc1[2]), f2bf(acc1[3])};
      *(ushort4*)&qs_lds[lr][c] = o0;
      *(ushort4*)&qs_lds[16 + lr][c] = o1;
    } else if (ntg < 48) {  // K/V -> fp8 e4m3, interleaved chunk layout
      bool isK = ntg < 32;
      int c = (isK ? (ntg - 16) : (ntg - 32)) * 16 + lq * 4;
      int pos = ((c >> 3) << 4) + (isK ? 0 : 8) + (c & 7);
      int p0 = __builtin_amdgcn_cvt_pk_fp8_f32(acc0[0], acc0[1], 0, false);
      p0 = __builtin_amdgcn_cvt_pk_fp8_f32(acc0[2], acc0[3], p0, true);
      int p1 = __builtin_amdgcn_cvt_pk_fp8_f32(acc1[0], acc1[1], 0, false);
      p1 = __builtin_amdgcn_cvt_pk_fp8_f32(acc1[2], acc1[3], p1, true);
      *(unsigned*)&kv_lds[lr][pos] = (unsigned)p0;
      *(unsigned*)&kv_lds[16 + lr][pos] = (unsigned)p1;
    } else {  // skip -> bf16 (qs cols 256..319)
      int c = 256 + (ntg - 48) * 16 + lq * 4;
      ushort4 o0{f2bf(acc0[0]), f2bf(acc0[1]), f2bf(acc0[2]), f2bf(acc0[3])};
      ushort4 o1{f2bf(acc1[0]), f2bf(acc1[1]), f2bf(acc1[2]), f2bf(acc1[3])};
      *(ushort4*)&qs_lds[lr][c] = o0;
      *(ushort4*)&qs_lds[16 + lr][c] = o1;
    }
#pragma unroll
    for (int kt = 0; kt < KT; kt++) bw[kt] = bwn[kt];
    b4 = b4n;
  }
  __syncthreads();
  int rows_here = n - m0;
  if (rows_here > 32) rows_here = 32;
  // qs out: rows are 640B dense -> contiguous 20KB per full block
  const char* qsl = (const char*)qs_lds;
  char* qout = (char*)Cq + (long long)m0 * (QS_ROW * 2);
#pragma unroll 1
  for (int off = tid * 16; off < 32 * 640; off += 4096) {
    int row = off / 640;
    if (row >= rows_here) break;
    int col = off - row * 640;
    uint4 v = *(const uint4*)(qsl + row * (QS_STR * 2) + col);
    *(uint4*)(qout + off) = v;
  }
  // kv out: rows 512B dense -> contiguous 16KB per full block
  const char* kvl = (const char*)kv_lds;
  char* kout = (char*)Ckv + (long long)m0 * KV_ROW;
#pragma unroll 1
  for (int off = tid * 16; off < 32 * 512; off += 4096) {
    int row = off >> 9;
    if (row >= rows_here) break;
    int col = off & 511;
    uint4 v = *(const uint4*)(kvl + row * KV_STR + col);
    *(uint4*)(kout + off) = v;
  }
}

// ---------------- fused attention + head-mean + skip + relu ----------------
// 1 node/wave. lane = half*32 + sl; chunk sl holds K[8ch]|V[8ch] in one 16B load.
// Per iteration: 8 edges (4 per half), packed f32x2 math, defer-max softmax.
__global__ __launch_bounds__(256) void attn_k(const ushort_t* __restrict__ qs,
                                              const unsigned char* __restrict__ kv,
                                              const int* __restrict__ rowp, const int* __restrict__ srt,
                                              ushort_t* __restrict__ hn, int n) {
  int wvv = __builtin_amdgcn_readfirstlane((int)(threadIdx.x >> 6));
  int node = blockIdx.x * 4 + wvv;
  if (node >= n) return;
  int lane = threadIdx.x & 63;
  int half = lane >> 5;
  int sl = lane & 31;
  const uint4 qu = *(const uint4*)(qs + (long long)node * QS_ROW + sl * 8);
  f32x2 qf[4];
  qf[0] = f32x2{blo(qu.x), bhi(qu.x)} * 0.125f;  // 1/sqrt(64) prescaled
  qf[1] = f32x2{blo(qu.y), bhi(qu.y)} * 0.125f;
  qf[2] = f32x2{blo(qu.z), bhi(qu.z)} * 0.125f;
  qf[3] = f32x2{blo(qu.w), bhi(qu.w)} * 0.125f;
  int rs = rowp[node], re = rowp[node + 1];
  int last = re - 1;
  unsigned nm1 = (unsigned)(n - 1);
  float m = -INFINITY, d = 0.f;
  f32x2 a2[4];
#pragma unroll
  for (int j = 0; j < 4; j++) a2[j] = f32x2{0.f, 0.f};

  for (int i = rs; i < re; i += 8) {
    int b0 = i + half * 4;
    // value-clamped indices (srt has >=12B tail slack inside d_ws)
    unsigned i0 = min((unsigned)srt[b0], nm1);
    unsigned i1 = min((unsigned)srt[b0 + 1], nm1);
    unsigned i2 = min((unsigned)srt[b0 + 2], nm1);
    unsigned i3 = min((unsigned)srt[b0 + 3], nm1);
    uint4 u0 = *(const uint4*)(kv + (long long)i0 * KV_ROW + sl * 16);
    uint4 u1 = *(const uint4*)(kv + (long long)i1 * KV_ROW + sl * 16);
    uint4 u2 = *(const uint4*)(kv + (long long)i2 * KV_ROW + sl * 16);
    uint4 u3 = *(const uint4*)(kv + (long long)i3 * KV_ROW + sl * 16);
    f32x2 kf0[4], kf1[4], kf2[4], kf3[4];
    dec8v(u0.x, u0.y, kf0); dec8v(u1.x, u1.y, kf1);
    dec8v(u2.x, u2.y, kf2); dec8v(u3.x, u3.y, kf3);
    f32x2 s0 = qf[0] * kf0[0], s1 = qf[0] * kf1[0], s2 = qf[0] * kf2[0], s3 = qf[0] * kf3[0];
#pragma unroll
    for (int j = 1; j < 4; j++) {
      s0 = s0 + qf[j] * kf0[j];
      s1 = s1 + qf[j] * kf1[j];
      s2 = s2 + qf[j] * kf2[j];
      s3 = s3 + qf[j] * kf3[j];
    }
    float t0 = s0[0] + s0[1], t1 = s1[0] + s1[1], t2 = s2[0] + s2[1], t3 = s3[0] + s3[1];
    t0 += __shfl_xor(t0, 1); t1 += __shfl_xor(t1, 1); t2 += __shfl_xor(t2, 1); t3 += __shfl_xor(t3, 1);
    t0 += __shfl_xor(t0, 2); t1 += __shfl_xor(t1, 2); t2 += __shfl_xor(t2, 2); t3 += __shfl_xor(t3, 2);
    t0 += __shfl_xor(t0, 4); t1 += __shfl_xor(t1, 4); t2 += __shfl_xor(t2, 4); t3 += __shfl_xor(t3, 4);
    if (b0 > last) t0 = -INFINITY;
    if (b0 + 1 > last) t1 = -INFINITY;
    if (b0 + 2 > last) t2 = -INFINITY;
    if (b0 + 3 > last) t3 = -INFINITY;
    float lm = fmaxf(fmaxf(t0, t1), fmaxf(t2, t3));
    lm = fmaxf(lm, __shfl_xor(lm, 32));
    if (__any(lm > m + 8.f)) {  // defer-max: rescale only on significant growth
      float mn = fmaxf(m, lm);
      float co = __expf(m - mn);  // first iter: exp(-inf)=0
      d *= co;
#pragma unroll
      for (int j = 0; j < 4; j++) a2[j] = a2[j] * co;
      m = mn;
    }
    float p0e = __expf(t0 - m), p1e = __expf(t1 - m), p2e = __expf(t2 - m), p3e = __expf(t3 - m);
    d += (p0e + p1e) + (p2e + p3e);
    f32x2 vf0[4], vf1[4], vf2[4], vf3[4];
    dec8v(u0.z, u0.w, vf0); dec8v(u1.z, u1.w, vf1);
    dec8v(u2.z, u2.w, vf2); dec8v(u3.z, u3.w, vf3);
    f32x2 pe0 = {p0e, p0e}, pe1 = {p1e, p1e}, pe2 = {p2e, p2e}, pe3 = {p3e, p3e};
#pragma unroll
    for (int j = 0; j < 4; j++)
      a2[j] = a2[j] + (pe0 * vf0[j] + pe1 * vf1[j]) + (pe2 * vf2[j] + pe3 * vf3[j]);
  }
  // merge halves (same chunk at lane^32)
  d += __shfl_xor(d, 32);
  float a[8];
#pragma unroll
  for (int j = 0; j < 4; j++) {
    a[2 * j] = a2[j][0] + __shfl_xor(a2[j][0], 32);
    a[2 * j + 1] = a2[j][1] + __shfl_xor(a2[j][1], 32);
  }
  float inv = (d > 0.f) ? 1.f / d : 0.f;
  float r[8];
#pragma unroll
  for (int j = 0; j < 8; j++) {
    r[j] = a[j] * inv;
    r[j] += __shfl_xor(r[j], 8);   // head ^1
    r[j] += __shfl_xor(r[j], 16);  // head ^2
  }
  if (lane < 8) {
    const u16x8 s8 = *(const u16x8*)(qs + (long long)node * QS_ROW + 256 + lane * 8);
    u16x8 o;
#pragma unroll
    for (int j = 0; j < 8; j++)
      o[j] = f2bf(fmaxf(r[j] * 0.25f + bf2f(s8[j]), 0.f));
    *(u16x8*)(hn + (long long)node * HID + lane * 8) = o;
  }
}

// ---------------- global add pool (run-length; batch is sorted) ----------------
#define POOL_NPB 128
__global__ __launch_bounds__(64) void pool_k(const ushort_t* __restrict__ h, const int* __restrict__ batch,
                                             float* __restrict__ out, int n) {
  int c = threadIdx.x;
  int n0 = blockIdx.x * POOL_NPB;
  int n1 = n0 + POOL_NPB;
  if (n1 > n) n1 = n;
  if (n0 >= n) return;
  float acc = 0.f;
  int g = batch[n0];
  for (int node = n0; node < n1; node++) {
    int gb = batch[node];
    if (gb != g) {
      atomicAdd(&out[g * 64 + c], acc);
      acc = 0.f;
      g = gb;
    }
    acc += bf2f(h[(long long)node * 64 + c]);
  }
  atomicAdd(&out[g * 64 + c], acc);
}

extern "C" void kernel_launch(void* const* d_in, const int* in_sizes, int n_in,
                              void* d_out, int out_size, void* d_ws, size_t ws_size,
                              hipStream_t stream) {
  const float* x  = (const float*)d_in[0];
  const int* ei   = (const int*)d_in[1];
  const int* batch = (const int*)d_in[2];
  const float* w0 = (const float*)d_in[3];
  const float* b0 = (const float*)d_in[4];
  const float* Wq = (const float*)d_in[5];
  const float* bq = (const float*)d_in[6];
  const float* Wk = (const float*)d_in[7];
  const float* bk = (const float*)d_in[8];
  const float* Wv = (const float*)d_in[9];
  const float* bv = (const float*)d_in[10];
  const float* Ws = (const float*)d_in[11];
  const float* bs = (const float*)d_in[12];
  int N = in_sizes[0] / F_IN;
  int E = in_sizes[1] / 2;
  const int* esrc = ei;
  const int* edst = ei + E;

  // ---- workspace layout ----
  float* bp = (float*)d_ws;                                   // 3*832 f32
  unsigned char* kvb = (unsigned char*)(bp + 3 * QSW);        // N*512 fp8
  ushort_t* ha = (ushort_t*)(kvb + (size_t)N * KV_ROW);
  ushort_t* hb = ha + (long long)N * HID;
  ushort_t* qs = hb + (long long)N * HID;                     // N x 320 bf16
  ushort_t* wp0  = qs + (long long)N * QS_ROW;                // 208 * 512
  ushort_t* wp12 = wp0 + 208 * 512;                           // 2 * 104 * 512
  int* cnt  = (int*)(wp12 + 2 * 104 * 512);
  int* excl = cnt + N;
  int* rowp = excl + N;
  int* bsum = rowp + N + 1;
  int* rank = bsum + 64;                                      // E ints
  int* srt  = rank + E;                                       // E ints (+tail slack in ws)

  int nbE = (E + 255) / 256;
  int sbBlocks = (N + 1023) / 1024;

  // CSR by dst (separate kernels for attribution + full occupancy)
  hipMemsetAsync(cnt, 0, (size_t)N * sizeof(int), stream);
  hist_rank_k<<<nbE, 256, 0, stream>>>(edst, cnt, rank, E);
  scan_block_k<<<sbBlocks, 1024, 0, stream>>>(cnt, excl, bsum, N);
  scatter_rowptr_k<<<nbE, 256, 0, stream>>>(esrc, edst, excl, bsum, rank, rowp, srt, N, E, sbBlocks);

  // weight packing + lin0 composition (parallel compose: 4 waves split j-loop)
  pack2_k<<<419, 256, 0, stream>>>(Wq, Wk, Wv, Ws, w0, b0, bq, bk, bv, bs, wp0, wp12, bp);

  int gBlocks = (N + 31) / 32;  // 1 block = 32 rows x 832 cols (LDS 37.9KB)

  // layer 0: composed weights, A = x fp32 direct (K=128)
  gemm_fused<128, 1><<<gBlocks, 256, 0, stream>>>(x, wp0, bp, qs, kvb, N);
  attn_k<<<(N + 3) / 4, 256, 0, stream>>>(qs, kvb, rowp, srt, ha, N);
  // layer 1
  gemm_fused<64, 0><<<gBlocks, 256, 0, stream>>>(ha, wp12, bp + QSW, qs, kvb, N);
  attn_k<<<(N + 3) / 4, 256, 0, stream>>>(qs, kvb, rowp, srt, hb, N);
  // layer 2
  gemm_fused<64, 0><<<gBlocks, 256, 0, stream>>>(hb, wp12 + 104 * 512, bp + 2 * QSW, qs, kvb, N);
  attn_k<<<(N + 3) / 4, 256, 0, stream>>>(qs, kvb, rowp, srt, ha, N);

  hipMemsetAsync(d_out, 0, (size_t)out_size * sizeof(float), stream);
  pool_k<<<(N + POOL_NPB - 1) / POOL_NPB, 64, 0, stream>>>(ha, batch, (float*)d_out, N);
}

// Round 18
// 308.595 us; speedup vs baseline: 1.0524x; 1.0002x over previous
//
#include <hip/hip_runtime.h>
#include <math.h>

#define F_IN 128
#define HID 64
#define NLAYER 3
#define QSW 832     // fused gemm output cols: q(256)|k(256)|v(256)|skip(64)
#define QS_ROW 320  // qs row: q(256)|skip(64) bf16
#define KV_ROW 512  // kv row: 32 chunks x (8B K | 8B V) fp8, interleaved

typedef unsigned short ushort_t;
typedef __bf16 bf16x8 __attribute__((ext_vector_type(8)));
typedef unsigned short u16x8 __attribute__((ext_vector_type(8)));
typedef float f32x4 __attribute__((ext_vector_type(4)));
typedef float f32x2 __attribute__((ext_vector_type(2)));

__device__ __forceinline__ ushort_t f2bf(float f) {
  unsigned u = __float_as_uint(f);
  u += 0x7fffu + ((u >> 16) & 1u);  // RNE; inputs finite
  return (ushort_t)(u >> 16);
}
__device__ __forceinline__ float bf2f(ushort_t s) {
  return __uint_as_float(((unsigned)s) << 16);
}
__device__ __forceinline__ float blo(unsigned u) { return __uint_as_float(u << 16); }
__device__ __forceinline__ float bhi(unsigned u) { return __uint_as_float(u & 0xffff0000u); }

// decode 8 fp8(e4m3) bytes (one uint2) -> 4 x f32x2
__device__ __forceinline__ void dec8v(unsigned lo, unsigned hi, f32x2* f) {
  f[0] = __builtin_amdgcn_cvt_pk_f32_fp8((int)lo, false);
  f[1] = __builtin_amdgcn_cvt_pk_f32_fp8((int)lo, true);
  f[2] = __builtin_amdgcn_cvt_pk_f32_fp8((int)hi, false);
  f[3] = __builtin_amdgcn_cvt_pk_f32_fp8((int)hi, true);
}

// ---------------- CSR: hist + per-edge rank (standalone, full occupancy) ----------------
__global__ __launch_bounds__(256) void hist_rank_k(const int* __restrict__ dst, int* __restrict__ cnt,
                                                   int* __restrict__ rank, int e) {
  int i = blockIdx.x * 256 + threadIdx.x;
  if (i < e) rank[i] = atomicAdd(&cnt[dst[i]], 1);
}

// ---------------- block scan: wave-shfl based (2 barriers) ----------------
__global__ __launch_bounds__(1024) void scan_block_k(const int* __restrict__ cnt, int* __restrict__ excl,
                                                     int* __restrict__ bsum, int n) {
  __shared__ int wsum[16];
  int t = threadIdx.x;
  int wv = t >> 6, lane = t & 63;
  int i = blockIdx.x * 1024 + t;
  int orig = (i < n) ? cnt[i] : 0;
  int v = orig;
#pragma unroll
  for (int off = 1; off < 64; off <<= 1) {
    int u = __shfl_up(v, off);
    if (lane >= off) v += u;
  }
  if (lane == 63) wsum[wv] = v;
  __syncthreads();
  if (t < 16) {
    int s = wsum[t];
    int s2 = s;
#pragma unroll
    for (int off = 1; off < 16; off <<= 1) {
      int u = __shfl_up(s2, off);
      if (t >= off) s2 += u;
    }
    wsum[t] = s2 - s;  // exclusive prefix of wave sums
  }
  __syncthreads();
  int base = wsum[wv];
  if (i < n) excl[i] = base + v - orig;
  if (t == 1023) bsum[blockIdx.x] = base + v;
}

// ---------------- fused: bsum scan + rowp finalize + atomic-free scatter ----------------
__global__ __launch_bounds__(256) void scatter_rowptr_k(const int* __restrict__ src, const int* __restrict__ dst,
                                                        const int* __restrict__ excl, const int* __restrict__ bsum,
                                                        const int* __restrict__ rank, int* __restrict__ rowp,
                                                        int* __restrict__ srt, int n, int e, int nb) {
  __shared__ int sb[64];
  int t = threadIdx.x;
  if (t < 64) {  // wave 0: exclusive scan of <=64 block sums
    int orig = (t < nb) ? bsum[t] : 0;
    int v = orig;
#pragma unroll
    for (int off = 1; off < 64; off <<= 1) {
      int u = __shfl_up(v, off);
      if (t >= off) v += u;
    }
    sb[t] = v - orig;
  }
  __syncthreads();
  int i = blockIdx.x * 256 + t;
  if (i < n) rowp[i] = excl[i] + sb[i >> 10];
  if (i == 0) rowp[n] = e;
  if (i < e) {
    int d = dst[i];
    srt[excl[d] + sb[d >> 10] + rank[i]] = src[i];
  }
}

// ---------------- weight packing + lin0 composition (one pack-unit per block) ----------------
// Blocks 0..207: layer-0 COMPOSED tiles Wc = w0 @ [Wq|Wk|Wv|Ws]; 4 waves split
//   the 64-deep j-loop 16 each, partials reduced through LDS (4x shorter chain).
// Blocks 208..415: layers 1,2 plain tile copy (wave 0 only; trivial).
// Blocks 416..418: bias rows (wave 0; layer 0 composed via shfl broadcast).
__global__ __launch_bounds__(256) void pack2_k(const float* __restrict__ Wq, const float* __restrict__ Wk,
                                               const float* __restrict__ Wv, const float* __restrict__ Ws,
                                               const float* __restrict__ w0, const float* __restrict__ b0,
                                               const float* __restrict__ bq, const float* __restrict__ bk,
                                               const float* __restrict__ bv, const float* __restrict__ bs,
                                               ushort_t* __restrict__ wp0, ushort_t* __restrict__ wp12,
                                               float* __restrict__ bp) {
  __shared__ float w0s[32 * 64];      // 8KB: w0 rows [kt*32, kt*32+32)
  __shared__ float part[3][64][8];    // 6KB: partial sums from waves 1..3
  int b = blockIdx.x;
  int t = threadIdx.x;
  int wv = t >> 6, lane = t & 63;
  if (b < 208) {  // ---- layer-0 compose ----
    int ntg = b >> 2, kt = b & 3;
    {  // stage w0 rows kt*32..+32 (2048 floats, coalesced)
      int base = kt * 32 * 64;
      int idx = t * 8;
      *(float4*)&w0s[idx] = *(const float4*)(w0 + base + idx);
      *(float4*)&w0s[idx + 4] = *(const float4*)(w0 + base + idx + 4);
    }
    __syncthreads();
    int col = ntg * 16 + (lane & 15);
    int kbl = (lane >> 4) * 8;  // local row base within the staged 32 rows
    const float* W; int c, stride;
    if (col < 256)      { W = Wq; c = col;       stride = 256; }
    else if (col < 512) { W = Wk; c = col - 256; stride = 256; }
    else if (col < 768) { W = Wv; c = col - 512; stride = 256; }
    else                { W = Ws; c = col - 768; stride = 64; }
    float vals[8] = {0.f, 0.f, 0.f, 0.f, 0.f, 0.f, 0.f, 0.f};
#pragma unroll 4
    for (int jj = 0; jj < 16; jj++) {
      int j = wv * 16 + jj;
      float wj = W[(long long)j * stride + c];
#pragma unroll
      for (int ee = 0; ee < 8; ee++) vals[ee] = fmaf(w0s[(kbl + ee) * 64 + j], wj, vals[ee]);
    }
    if (wv > 0) {
#pragma unroll
      for (int ee = 0; ee < 8; ee++) part[wv - 1][lane][ee] = vals[ee];
    }
    __syncthreads();
    if (wv == 0) {
#pragma unroll
      for (int ee = 0; ee < 8; ee++)
        vals[ee] += part[0][lane][ee] + part[1][lane][ee] + part[2][lane][ee];
      ushort_t* p = wp0 + ((long long)b * 64 + lane) * 8;
      ushort4 lo{f2bf(vals[0]), f2bf(vals[1]), f2bf(vals[2]), f2bf(vals[3])};
      ushort4 hi{f2bf(vals[4]), f2bf(vals[5]), f2bf(vals[6]), f2bf(vals[7])};
      *(ushort4*)p = lo;
      *(ushort4*)(p + 4) = hi;
    }
  } else if (b < 416) {  // ---- layers 1,2 plain pack (wave 0) ----
    if (wv != 0) return;
    int idx = b - 208;
    int l = 1 + idx / 104, tt = idx % 104;
    int ntg = tt >> 1, kt = tt & 1;
    int col = ntg * 16 + (lane & 15);
    int kb = kt * 32 + (lane >> 4) * 8;
    const float* W; int c, stride;
    if (col < 256)      { W = Wq + (long long)l * 64 * 256; c = col;       stride = 256; }
    else if (col < 512) { W = Wk + (long long)l * 64 * 256; c = col - 256; stride = 256; }
    else if (col < 768) { W = Wv + (long long)l * 64 * 256; c = col - 512; stride = 256; }
    else                { W = Ws + (long long)l * 64 * 64;  c = col - 768; stride = 64; }
    float vals[8];
#pragma unroll
    for (int ee = 0; ee < 8; ee++) vals[ee] = W[(long long)(kb + ee) * stride + c];
    ushort_t* p = wp12 + (long long)(l - 1) * (104 * 512) + ((long long)tt * 64 + lane) * 8;
    ushort4 lo{f2bf(vals[0]), f2bf(vals[1]), f2bf(vals[2]), f2bf(vals[3])};
    ushort4 hi{f2bf(vals[4]), f2bf(vals[5]), f2bf(vals[6]), f2bf(vals[7])};
    *(ushort4*)p = lo;
    *(ushort4*)(p + 4) = hi;
  } else {  // ---- bias rows (wave 0) ----
    if (wv != 0) return;
    int l = b - 416;
    if (l == 0) {  // composed bias: bc = b0 @ W + b (b0 via register shuffle)
      float b0v = b0[lane];
      for (int c = lane; c < QSW; c += 64) {
        const float* W; const float* borig; int cc, stride;
        if (c < 256)      { W = Wq; borig = bq; cc = c;       stride = 256; }
        else if (c < 512) { W = Wk; borig = bk; cc = c - 256; stride = 256; }
        else if (c < 768) { W = Wv; borig = bv; cc = c - 512; stride = 256; }
        else              { W = Ws; borig = bs; cc = c - 768; stride = 64; }
        float acc = borig[cc];
#pragma unroll 4
        for (int j = 0; j < 64; j++)
          acc = fmaf(__shfl(b0v, j), W[(long long)j * stride + cc], acc);
        bp[c] = acc;
      }
    } else {
      for (int c = lane; c < QSW; c += 64) {
        float v = (c < 256) ? bq[l * 256 + c]
                : (c < 512) ? bk[l * 256 + c - 256]
                : (c < 768) ? bv[l * 256 + c - 512]
                : bs[l * 64 + c - 768];
        bp[l * QSW + c] = v;
      }
    }
  }
}

// ---------------- fused MFMA GEMM with LDS-staged coalesced epilogue ----------------
// Block = 32 rows x all 832 cols; 4 waves split the 52 col-tiles (13 each).
// LDS 37.9KB + VGPR ~104 -> 4 blocks/CU. MR=2 fragments/wave; depth-1 W
// prefetch in NAMED registers. K/V stored interleaved per 8-ch chunk.
#define QS_STR 328  // ushorts: 656B row stride
#define KV_STR 528  // bytes: 16B-aligned
template <int K, int AF32>
__global__ __launch_bounds__(256) void gemm_fused(const void* __restrict__ Av, const ushort_t* __restrict__ Wp,
                                                  const float* __restrict__ bias, ushort_t* __restrict__ Cq,
                                                  unsigned char* __restrict__ Ckv, int n) {
  constexpr int KT = K / 32;
  __shared__ ushort_t qs_lds[32][QS_STR];
  __shared__ unsigned char kv_lds[32][KV_STR];
  int tid = threadIdx.x;
  int lane = tid & 63;
  int wv = __builtin_amdgcn_readfirstlane((int)(tid >> 6));
  int m0 = blockIdx.x * 32;
  int lr = lane & 15, lq = lane >> 4;

  bf16x8 a[2][KT];
#pragma unroll
  for (int mr = 0; mr < 2; mr++) {
    int row = m0 + mr * 16 + lr;
    if (row >= n) row = n - 1;
    if constexpr (AF32) {
      const float* Af = (const float*)Av;
#pragma unroll
      for (int kt = 0; kt < KT; kt++) {
        const float* p = Af + (long long)row * K + kt * 32 + lq * 8;
        float4 f0 = *(const float4*)p;
        float4 f1 = *(const float4*)(p + 4);
        u16x8 u;
        u[0] = f2bf(f0.x); u[1] = f2bf(f0.y); u[2] = f2bf(f0.z); u[3] = f2bf(f0.w);
        u[4] = f2bf(f1.x); u[5] = f2bf(f1.y); u[6] = f2bf(f1.z); u[7] = f2bf(f1.w);
        a[mr][kt] = __builtin_bit_cast(bf16x8, u);
      }
    } else {
      const ushort_t* Ab = (const ushort_t*)Av;
#pragma unroll
      for (int kt = 0; kt < KT; kt++)
        a[mr][kt] = *(const bf16x8*)(Ab + (long long)row * K + kt * 32 + lq * 8);
    }
  }
  int ntg0 = wv * 13;
  bf16x8 bw[KT];   // current tile W-frags (named, compile-time indexed)
  bf16x8 bwn[KT];  // next tile
#pragma unroll
  for (int kt = 0; kt < KT; kt++)
    bw[kt] = *(const bf16x8*)(Wp + ((long long)(ntg0 * KT + kt) * 64 + lane) * 8);
  float4 b4 = *(const float4*)(bias + ntg0 * 16 + lq * 4);
#pragma unroll 1
  for (int t = 0; t < 13; t++) {
    int ntg = ntg0 + t;
    float4 b4n;
    if (t < 12) {  // prefetch next tile's W + bias into named regs
#pragma unroll
      for (int kt = 0; kt < KT; kt++)
        bwn[kt] = *(const bf16x8*)(Wp + ((long long)((ntg + 1) * KT + kt) * 64 + lane) * 8);
      b4n = *(const float4*)(bias + (ntg + 1) * 16 + lq * 4);
    }
    f32x4 acc0 = {b4.x, b4.y, b4.z, b4.w};
    f32x4 acc1 = acc0;
#pragma unroll
    for (int kt = 0; kt < KT; kt++) {
      acc0 = __builtin_amdgcn_mfma_f32_16x16x32_bf16(bw[kt], a[0][kt], acc0, 0, 0, 0);
      acc1 = __builtin_amdgcn_mfma_f32_16x16x32_bf16(bw[kt], a[1][kt], acc1, 0, 0, 0);
    }
    if (ntg < 16) {  // q -> bf16
      int c = ntg * 16 + lq * 4;
      ushort4 o0{f2bf(acc0[0]), f2bf(acc0[1]), f2bf(acc0[2]), f2bf(acc0[3])};
      ushort4 o1{f2bf(acc1[0]), f2bf(acc1[1]), f2bf(acc1[2]), f2bf(acc1[3])};
      *(ushort4*)&qs_lds[lr][c] = o0;
      *(ushort4*)&qs_lds[16 + lr][c] = o1;
    } else if (ntg < 48) {  // K/V -> fp8 e4m3, interleaved chunk layout
      bool isK = ntg < 32;
      int c = (isK ? (ntg - 16) : (ntg - 32)) * 16 + lq * 4;
      int pos = ((c >> 3) << 4) + (isK ? 0 : 8) + (c & 7);
      int p0 = __builtin_amdgcn_cvt_pk_fp8_f32(acc0[0], acc0[1], 0, false);
      p0 = __builtin_amdgcn_cvt_pk_fp8_f32(acc0[2], acc0[3], p0, true);
      int p1 = __builtin_amdgcn_cvt_pk_fp8_f32(acc1[0], acc1[1], 0, false);
      p1 = __builtin_amdgcn_cvt_pk_fp8_f32(acc1[2], acc1[3], p1, true);
      *(unsigned*)&kv_lds[lr][pos] = (unsigned)p0;
      *(unsigned*)&kv_lds[16 + lr][pos] = (unsigned)p1;
    } else {  // skip -> bf16 (qs cols 256..319)
      int c = 256 + (ntg - 48) * 16 + lq * 4;
      ushort4 o0{f2bf(acc0[0]), f2bf(acc0[1]), f2bf(acc0[2]), f2bf(acc0[3])};
      ushort4 o1{f2bf(acc1[0]), f2bf(acc1[1]), f2bf(acc1[2]), f2bf(acc1[3])};
      *(ushort4*)&qs_lds[lr][c] = o0;
      *(ushort4*)&qs_lds[16 + lr][c] = o1;
    }
#pragma unroll
    for (int kt = 0; kt < KT; kt++) bw[kt] = bwn[kt];
    b4 = b4n;
  }
  __syncthreads();
  int rows_here = n - m0;
  if (rows_here > 32) rows_here = 32;
  // qs out: rows are 640B dense -> contiguous 20KB per full block
  const char* qsl = (const char*)qs_lds;
  char* qout = (char*)Cq + (long long)m0 * (QS_ROW * 2);
#pragma unroll 1
  for (int off = tid * 16; off < 32 * 640; off += 4096) {
    int row = off / 640;
    if (row >= rows_here) break;
    int col = off - row * 640;
    uint4 v = *(const uint4*)(qsl + row * (QS_STR * 2) + col);
    *(uint4*)(qout + off) = v;
  }
  // kv out: rows 512B dense -> contiguous 16KB per full block
  const char* kvl = (const char*)kv_lds;
  char* kout = (char*)Ckv + (long long)m0 * KV_ROW;
#pragma unroll 1
  for (int off = tid * 16; off < 32 * 512; off += 4096) {
    int row = off >> 9;
    if (row >= rows_here) break;
    int col = off & 511;
    uint4 v = *(const uint4*)(kvl + row * KV_STR + col);
    *(uint4*)(kout + off) = v;
  }
}

// ---------------- fused attention + head-mean + skip + relu ----------------
// 1 node/wave. lane = half*32 + sl; chunk sl holds K[8ch]|V[8ch] in one 16B load.
// Per iteration: 8 edges (4 per half), packed f32x2 math, defer-max softmax.
__global__ __launch_bounds__(256) void attn_k(const ushort_t* __restrict__ qs,
                                              const unsigned char* __restrict__ kv,
                                              const int* __restrict__ rowp, const int* __restrict__ srt,
                                              ushort_t* __restrict__ hn, int n) {
  int wvv = __builtin_amdgcn_readfirstlane((int)(threadIdx.x >> 6));
  int node = blockIdx.x * 4 + wvv;
  if (node >= n) return;
  int lane = threadIdx.x & 63;
  int half = lane >> 5;
  int sl = lane & 31;
  const uint4 qu = *(const uint4*)(qs + (long long)node * QS_ROW + sl * 8);
  f32x2 qf[4];
  qf[0] = f32x2{blo(qu.x), bhi(qu.x)} * 0.125f;  // 1/sqrt(64) prescaled
  qf[1] = f32x2{blo(qu.y), bhi(qu.y)} * 0.125f;
  qf[2] = f32x2{blo(qu.z), bhi(qu.z)} * 0.125f;
  qf[3] = f32x2{blo(qu.w), bhi(qu.w)} * 0.125f;
  int rs = rowp[node], re = rowp[node + 1];
  int last = re - 1;
  unsigned nm1 = (unsigned)(n - 1);
  float m = -INFINITY, d = 0.f;
  f32x2 a2[4];
#pragma unroll
  for (int j = 0; j < 4; j++) a2[j] = f32x2{0.f, 0.f};

  for (int i = rs; i < re; i += 8) {
    int b0 = i + half * 4;
    // value-clamped indices (srt has >=12B tail slack inside d_ws)
    unsigned i0 = min((unsigned)srt[b0], nm1);
    unsigned i1 = min((unsigned)srt[b0 + 1], nm1);
    unsigned i2 = min((unsigned)srt[b0 + 2], nm1);
    unsigned i3 = min((unsigned)srt[b0 + 3], nm1);
    uint4 u0 = *(const uint4*)(kv + (long long)i0 * KV_ROW + sl * 16);
    uint4 u1 = *(const uint4*)(kv + (long long)i1 * KV_ROW + sl * 16);
    uint4 u2 = *(const uint4*)(kv + (long long)i2 * KV_ROW + sl * 16);
    uint4 u3 = *(const uint4*)(kv + (long long)i3 * KV_ROW + sl * 16);
    f32x2 kf0[4], kf1[4], kf2[4], kf3[4];
    dec8v(u0.x, u0.y, kf0); dec8v(u1.x, u1.y, kf1);
    dec8v(u2.x, u2.y, kf2); dec8v(u3.x, u3.y, kf3);
    f32x2 s0 = qf[0] * kf0[0], s1 = qf[0] * kf1[0], s2 = qf[0] * kf2[0], s3 = qf[0] * kf3[0];
#pragma unroll
    for (int j = 1; j < 4; j++) {
      s0 = s0 + qf[j] * kf0[j];
      s1 = s1 + qf[j] * kf1[j];
      s2 = s2 + qf[j] * kf2[j];
      s3 = s3 + qf[j] * kf3[j];
    }
    float t0 = s0[0] + s0[1], t1 = s1[0] + s1[1], t2 = s2[0] + s2[1], t3 = s3[0] + s3[1];
    t0 += __shfl_xor(t0, 1); t1 += __shfl_xor(t1, 1); t2 += __shfl_xor(t2, 1); t3 += __shfl_xor(t3, 1);
    t0 += __shfl_xor(t0, 2); t1 += __shfl_xor(t1, 2); t2 += __shfl_xor(t2, 2); t3 += __shfl_xor(t3, 2);
    t0 += __shfl_xor(t0, 4); t1 += __shfl_xor(t1, 4); t2 += __shfl_xor(t2, 4); t3 += __shfl_xor(t3, 4);
    if (b0 > last) t0 = -INFINITY;
    if (b0 + 1 > last) t1 = -INFINITY;
    if (b0 + 2 > last) t2 = -INFINITY;
    if (b0 + 3 > last) t3 = -INFINITY;
    float lm = fmaxf(fmaxf(t0, t1), fmaxf(t2, t3));
    lm = fmaxf(lm, __shfl_xor(lm, 32));
    if (__any(lm > m + 8.f)) {  // defer-max: rescale only on significant growth
      float mn = fmaxf(m, lm);
      float co = __expf(m - mn);  // first iter: exp(-inf)=0
      d *= co;
#pragma unroll
      for (int j = 0; j < 4; j++) a2[j] = a2[j] * co;
      m = mn;
    }
    float p0e = __expf(t0 - m), p1e = __expf(t1 - m), p2e = __expf(t2 - m), p3e = __expf(t3 - m);
    d += (p0e + p1e) + (p2e + p3e);
    f32x2 vf0[4], vf1[4], vf2[4], vf3[4];
    dec8v(u0.z, u0.w, vf0); dec8v(u1.z, u1.w, vf1);
    dec8v(u2.z, u2.w, vf2); dec8v(u3.z, u3.w, vf3);
    f32x2 pe0 = {p0e, p0e}, pe1 = {p1e, p1e}, pe2 = {p2e, p2e}, pe3 = {p3e, p3e};
#pragma unroll
    for (int j = 0; j < 4; j++)
      a2[j] = a2[j] + (pe0 * vf0[j] + pe1 * vf1[j]) + (pe2 * vf2[j] + pe3 * vf3[j]);
  }
  // merge halves (same chunk at lane^32)
  d += __shfl_xor(d, 32);
  float a[8];
#pragma unroll
  for (int j = 0; j < 4; j++) {
    a[2 * j] = a2[j][0] + __shfl_xor(a2[j][0], 32);
    a[2 * j + 1] = a2[j][1] + __shfl_xor(a2[j][1], 32);
  }
  float inv = (d > 0.f) ? 1.f / d : 0.f;
  float r[8];
#pragma unroll
  for (int j = 0; j < 8; j++) {
    r[j] = a[j] * inv;
    r[j] += __shfl_xor(r[j], 8);   // head ^1
    r[j] += __shfl_xor(r[j], 16);  // head ^2
  }
  if (lane < 8) {
    const u16x8 s8 = *(const u16x8*)(qs + (long long)node * QS_ROW + 256 + lane * 8);
    u16x8 o;
#pragma unroll
    for (int j = 0; j < 8; j++)
      o[j] = f2bf(fmaxf(r[j] * 0.25f + bf2f(s8[j]), 0.f));
    *(u16x8*)(hn + (long long)node * HID + lane * 8) = o;
  }
}

// ---------------- global add pool (run-length; batch is sorted) ----------------
#define POOL_NPB 128
__global__ __launch_bounds__(64) void pool_k(const ushort_t* __restrict__ h, const int* __restrict__ batch,
                                             float* __restrict__ out, int n) {
  int c = threadIdx.x;
  int n0 = blockIdx.x * POOL_NPB;
  int n1 = n0 + POOL_NPB;
  if (n1 > n) n1 = n;
  if (n0 >= n) return;
  float acc = 0.f;
  int g = batch[n0];
  for (int node = n0; node < n1; node++) {
    int gb = batch[node];
    if (gb != g) {
      atomicAdd(&out[g * 64 + c], acc);
      acc = 0.f;
      g = gb;
    }
    acc += bf2f(h[(long long)node * 64 + c]);
  }
  atomicAdd(&out[g * 64 + c], acc);
}

extern "C" void kernel_launch(void* const* d_in, const int* in_sizes, int n_in,
                              void* d_out, int out_size, void* d_ws, size_t ws_size,
                              hipStream_t stream) {
  const float* x  = (const float*)d_in[0];
  const int* ei   = (const int*)d_in[1];
  const int* batch = (const int*)d_in[2];
  const float* w0 = (const float*)d_in[3];
  const float* b0 = (const float*)d_in[4];
  const float* Wq = (const float*)d_in[5];
  const float* bq = (const float*)d_in[6];
  const float* Wk = (const float*)d_in[7];
  const float* bk = (const float*)d_in[8];
  const float* Wv = (const float*)d_in[9];
  const float* bv = (const float*)d_in[10];
  const float* Ws = (const float*)d_in[11];
  const float* bs = (const float*)d_in[12];
  int N = in_sizes[0] / F_IN;
  int E = in_sizes[1] / 2;
  const int* esrc = ei;
  const int* edst = ei + E;

  // ---- workspace layout ----
  float* bp = (float*)d_ws;                                   // 3*832 f32
  unsigned char* kvb = (unsigned char*)(bp + 3 * QSW);        // N*512 fp8
  ushort_t* ha = (ushort_t*)(kvb + (size_t)N * KV_ROW);
  ushort_t* hb = ha + (long long)N * HID;
  ushort_t* qs = hb + (long long)N * HID;                     // N x 320 bf16
  ushort_t* wp0  = qs + (long long)N * QS_ROW;                // 208 * 512
  ushort_t* wp12 = wp0 + 208 * 512;                           // 2 * 104 * 512
  int* cnt  = (int*)(wp12 + 2 * 104 * 512);
  int* excl = cnt + N;
  int* rowp = excl + N;
  int* bsum = rowp + N + 1;
  int* rank = bsum + 64;                                      // E ints
  int* srt  = rank + E;                                       // E ints (+tail slack in ws)

  int nbE = (E + 255) / 256;
  int sbBlocks = (N + 1023) / 1024;

  // CSR by dst (separate kernels for attribution + full occupancy)
  hipMemsetAsync(cnt, 0, (size_t)N * sizeof(int), stream);
  hist_rank_k<<<nbE, 256, 0, stream>>>(edst, cnt, rank, E);
  scan_block_k<<<sbBlocks, 1024, 0, stream>>>(cnt, excl, bsum, N);
  scatter_rowptr_k<<<nbE, 256, 0, stream>>>(esrc, edst, excl, bsum, rank, rowp, srt, N, E, sbBlocks);

  // weight packing + lin0 composition (parallel compose: 4 waves split j-loop)
  pack2_k<<<419, 256, 0, stream>>>(Wq, Wk, Wv, Ws, w0, b0, bq, bk, bv, bs, wp0, wp12, bp);

  int gBlocks = (N + 31) / 32;  // 1 block = 32 rows x 832 cols (LDS 37.9KB)

  // layer 0: composed weights, A = x fp32 direct (K=128)
  gemm_fused<128, 1><<<gBlocks, 256, 0, stream>>>(x, wp0, bp, qs, kvb, N);
  attn_k<<<(N + 3) / 4, 256, 0, stream>>>(qs, kvb, rowp, srt, ha, N);
  // layer 1
  gemm_fused<64, 0><<<gBlocks, 256, 0, stream>>>(ha, wp12, bp + QSW, qs, kvb, N);
  attn_k<<<(N + 3) / 4, 256, 0, stream>>>(qs, kvb, rowp, srt, hb, N);
  // layer 2
  gemm_fused<64, 0><<<gBlocks, 256, 0, stream>>>(hb, wp12 + 104 * 512, bp + 2 * QSW, qs, kvb, N);
  attn_k<<<(N + 3) / 4, 256, 0, stream>>>(qs, kvb, rowp, srt, ha, N);

  hipMemsetAsync(d_out, 0, (size_t)out_size * sizeof(float), stream);
  pool_k<<<(N + POOL_NPB - 1) / POOL_NPB, 64, 0, stream>>>(ha, batch, (float*)d_out, N);
}

// Round 19
// 301.432 us; speedup vs baseline: 1.0775x; 1.0238x over previous
//
#include <hip/hip_runtime.h>
#include <math.h>

#define F_IN 128
#define HID 64
#define NLAYER 3
#define QSW 832     // fused gemm output cols: q(256)|k(256)|v(256)|skip(64)
#define QS_ROW 320  // qs row: q(256)|skip(64) bf16
#define KV_ROW 512  // kv row: 32 chunks x (8B K | 8B V) fp8, interleaved

typedef unsigned short ushort_t;
typedef __bf16 bf16x8 __attribute__((ext_vector_type(8)));
typedef unsigned short u16x8 __attribute__((ext_vector_type(8)));
typedef float f32x4 __attribute__((ext_vector_type(4)));
typedef float f32x2 __attribute__((ext_vector_type(2)));

__device__ __forceinline__ ushort_t f2bf(float f) {
  unsigned u = __float_as_uint(f);
  u += 0x7fffu + ((u >> 16) & 1u);  // RNE; inputs finite
  return (ushort_t)(u >> 16);
}
__device__ __forceinline__ float bf2f(ushort_t s) {
  return __uint_as_float(((unsigned)s) << 16);
}
__device__ __forceinline__ float blo(unsigned u) { return __uint_as_float(u << 16); }
__device__ __forceinline__ float bhi(unsigned u) { return __uint_as_float(u & 0xffff0000u); }

// decode 8 fp8(e4m3) bytes (one uint2) -> 4 x f32x2
__device__ __forceinline__ void dec8v(unsigned lo, unsigned hi, f32x2* f) {
  f[0] = __builtin_amdgcn_cvt_pk_f32_fp8((int)lo, false);
  f[1] = __builtin_amdgcn_cvt_pk_f32_fp8((int)lo, true);
  f[2] = __builtin_amdgcn_cvt_pk_f32_fp8((int)hi, false);
  f[3] = __builtin_amdgcn_cvt_pk_f32_fp8((int)hi, true);
}

// ---------------- CSR: hist + per-edge rank (standalone, full occupancy) ----------------
__global__ __launch_bounds__(256) void hist_rank_k(const int* __restrict__ dst, int* __restrict__ cnt,
                                                   int* __restrict__ rank, int e) {
  int i = blockIdx.x * 256 + threadIdx.x;
  if (i < e) rank[i] = atomicAdd(&cnt[dst[i]], 1);
}

// ---------------- block scan: wave-shfl based (2 barriers) ----------------
__global__ __launch_bounds__(1024) void scan_block_k(const int* __restrict__ cnt, int* __restrict__ excl,
                                                     int* __restrict__ bsum, int n) {
  __shared__ int wsum[16];
  int t = threadIdx.x;
  int wv = t >> 6, lane = t & 63;
  int i = blockIdx.x * 1024 + t;
  int orig = (i < n) ? cnt[i] : 0;
  int v = orig;
#pragma unroll
  for (int off = 1; off < 64; off <<= 1) {
    int u = __shfl_up(v, off);
    if (lane >= off) v += u;
  }
  if (lane == 63) wsum[wv] = v;
  __syncthreads();
  if (t < 16) {
    int s = wsum[t];
    int s2 = s;
#pragma unroll
    for (int off = 1; off < 16; off <<= 1) {
      int u = __shfl_up(s2, off);
      if (t >= off) s2 += u;
    }
    wsum[t] = s2 - s;  // exclusive prefix of wave sums
  }
  __syncthreads();
  int base = wsum[wv];
  if (i < n) excl[i] = base + v - orig;
  if (t == 1023) bsum[blockIdx.x] = base + v;
}

// ---------------- fused: bsum scan + rowp finalize + atomic-free scatter ----------------
__global__ __launch_bounds__(256) void scatter_rowptr_k(const int* __restrict__ src, const int* __restrict__ dst,
                                                        const int* __restrict__ excl, const int* __restrict__ bsum,
                                                        const int* __restrict__ rank, int* __restrict__ rowp,
                                                        int* __restrict__ srt, int n, int e, int nb) {
  __shared__ int sb[64];
  int t = threadIdx.x;
  if (t < 64) {  // wave 0: exclusive scan of <=64 block sums
    int orig = (t < nb) ? bsum[t] : 0;
    int v = orig;
#pragma unroll
    for (int off = 1; off < 64; off <<= 1) {
      int u = __shfl_up(v, off);
      if (t >= off) v += u;
    }
    sb[t] = v - orig;
  }
  __syncthreads();
  int i = blockIdx.x * 256 + t;
  if (i < n) rowp[i] = excl[i] + sb[i >> 10];
  if (i == 0) rowp[n] = e;
  if (i < e) {
    int d = dst[i];
    srt[excl[d] + sb[d >> 10] + rank[i]] = src[i];
  }
}

// ---------------- weight packing + lin0 composition (one pack-unit per block) ----------------
__global__ __launch_bounds__(256) void pack2_k(const float* __restrict__ Wq, const float* __restrict__ Wk,
                                               const float* __restrict__ Wv, const float* __restrict__ Ws,
                                               const float* __restrict__ w0, const float* __restrict__ b0,
                                               const float* __restrict__ bq, const float* __restrict__ bk,
                                               const float* __restrict__ bv, const float* __restrict__ bs,
                                               ushort_t* __restrict__ wp0, ushort_t* __restrict__ wp12,
                                               float* __restrict__ bp) {
  __shared__ float w0s[32 * 64];      // 8KB: w0 rows [kt*32, kt*32+32)
  __shared__ float part[3][64][8];    // 6KB: partial sums from waves 1..3
  int b = blockIdx.x;
  int t = threadIdx.x;
  int wv = t >> 6, lane = t & 63;
  if (b < 208) {  // ---- layer-0 compose ----
    int ntg = b >> 2, kt = b & 3;
    {  // stage w0 rows kt*32..+32 (2048 floats, coalesced)
      int base = kt * 32 * 64;
      int idx = t * 8;
      *(float4*)&w0s[idx] = *(const float4*)(w0 + base + idx);
      *(float4*)&w0s[idx + 4] = *(const float4*)(w0 + base + idx + 4);
    }
    __syncthreads();
    int col = ntg * 16 + (lane & 15);
    int kbl = (lane >> 4) * 8;  // local row base within the staged 32 rows
    const float* W; int c, stride;
    if (col < 256)      { W = Wq; c = col;       stride = 256; }
    else if (col < 512) { W = Wk; c = col - 256; stride = 256; }
    else if (col < 768) { W = Wv; c = col - 512; stride = 256; }
    else                { W = Ws; c = col - 768; stride = 64; }
    float vals[8] = {0.f, 0.f, 0.f, 0.f, 0.f, 0.f, 0.f, 0.f};
#pragma unroll 4
    for (int jj = 0; jj < 16; jj++) {
      int j = wv * 16 + jj;
      float wj = W[(long long)j * stride + c];
#pragma unroll
      for (int ee = 0; ee < 8; ee++) vals[ee] = fmaf(w0s[(kbl + ee) * 64 + j], wj, vals[ee]);
    }
    if (wv > 0) {
#pragma unroll
      for (int ee = 0; ee < 8; ee++) part[wv - 1][lane][ee] = vals[ee];
    }
    __syncthreads();
    if (wv == 0) {
#pragma unroll
      for (int ee = 0; ee < 8; ee++)
        vals[ee] += part[0][lane][ee] + part[1][lane][ee] + part[2][lane][ee];
      ushort_t* p = wp0 + ((long long)b * 64 + lane) * 8;
      ushort4 lo{f2bf(vals[0]), f2bf(vals[1]), f2bf(vals[2]), f2bf(vals[3])};
      ushort4 hi{f2bf(vals[4]), f2bf(vals[5]), f2bf(vals[6]), f2bf(vals[7])};
      *(ushort4*)p = lo;
      *(ushort4*)(p + 4) = hi;
    }
  } else if (b < 416) {  // ---- layers 1,2 plain pack (wave 0) ----
    if (wv != 0) return;
    int idx = b - 208;
    int l = 1 + idx / 104, tt = idx % 104;
    int ntg = tt >> 1, kt = tt & 1;
    int col = ntg * 16 + (lane & 15);
    int kb = kt * 32 + (lane >> 4) * 8;
    const float* W; int c, stride;
    if (col < 256)      { W = Wq + (long long)l * 64 * 256; c = col;       stride = 256; }
    else if (col < 512) { W = Wk + (long long)l * 64 * 256; c = col - 256; stride = 256; }
    else if (col < 768) { W = Wv + (long long)l * 64 * 256; c = col - 512; stride = 256; }
    else                { W = Ws + (long long)l * 64 * 64;  c = col - 768; stride = 64; }
    float vals[8];
#pragma unroll
    for (int ee = 0; ee < 8; ee++) vals[ee] = W[(long long)(kb + ee) * stride + c];
    ushort_t* p = wp12 + (long long)(l - 1) * (104 * 512) + ((long long)tt * 64 + lane) * 8;
    ushort4 lo{f2bf(vals[0]), f2bf(vals[1]), f2bf(vals[2]), f2bf(vals[3])};
    ushort4 hi{f2bf(vals[4]), f2bf(vals[5]), f2bf(vals[6]), f2bf(vals[7])};
    *(ushort4*)p = lo;
    *(ushort4*)(p + 4) = hi;
  } else {  // ---- bias rows (wave 0) ----
    if (wv != 0) return;
    int l = b - 416;
    if (l == 0) {  // composed bias: bc = b0 @ W + b (b0 via register shuffle)
      float b0v = b0[lane];
      for (int c = lane; c < QSW; c += 64) {
        const float* W; const float* borig; int cc, stride;
        if (c < 256)      { W = Wq; borig = bq; cc = c;       stride = 256; }
        else if (c < 512) { W = Wk; borig = bk; cc = c - 256; stride = 256; }
        else if (c < 768) { W = Wv; borig = bv; cc = c - 512; stride = 256; }
        else              { W = Ws; borig = bs; cc = c - 768; stride = 64; }
        float acc = borig[cc];
#pragma unroll 4
        for (int j = 0; j < 64; j++)
          acc = fmaf(__shfl(b0v, j), W[(long long)j * stride + cc], acc);
        bp[c] = acc;
      }
    } else {
      for (int c = lane; c < QSW; c += 64) {
        float v = (c < 256) ? bq[l * 256 + c]
                : (c < 512) ? bk[l * 256 + c - 256]
                : (c < 768) ? bv[l * 256 + c - 512]
                : bs[l * 64 + c - 768];
        bp[l * QSW + c] = v;
      }
    }
  }
}

// ---------------- fused MFMA GEMM with LDS-staged coalesced epilogue ----------------
// Block = 32 rows x all 832 cols; 4 waves split the 52 col-tiles (13 each).
// KT==2: depth-3 W prefetch via 3 named buffers + inlined tile body (all
// register indices lexical). KT==4 (layer 0): depth-1 (VGPR budget).
#define QS_STR 328  // ushorts: 656B row stride
#define KV_STR 528  // bytes: 16B-aligned

// compute one col-tile (KT=2) from given W-frags/bias and stage to LDS
__device__ __forceinline__ void tile_body2(const bf16x8 (&a)[2][2], const bf16x8 (&bw)[2], float4 b4,
                                           int ntg, int lr, int lq,
                                           ushort_t (*qs_lds)[QS_STR], unsigned char (*kv_lds)[KV_STR]) {
  f32x4 acc0 = {b4.x, b4.y, b4.z, b4.w};
  f32x4 acc1 = acc0;
  acc0 = __builtin_amdgcn_mfma_f32_16x16x32_bf16(bw[0], a[0][0], acc0, 0, 0, 0);
  acc1 = __builtin_amdgcn_mfma_f32_16x16x32_bf16(bw[0], a[1][0], acc1, 0, 0, 0);
  acc0 = __builtin_amdgcn_mfma_f32_16x16x32_bf16(bw[1], a[0][1], acc0, 0, 0, 0);
  acc1 = __builtin_amdgcn_mfma_f32_16x16x32_bf16(bw[1], a[1][1], acc1, 0, 0, 0);
  if (ntg < 16) {  // q -> bf16
    int c = ntg * 16 + lq * 4;
    ushort4 o0{f2bf(acc0[0]), f2bf(acc0[1]), f2bf(acc0[2]), f2bf(acc0[3])};
    ushort4 o1{f2bf(acc1[0]), f2bf(acc1[1]), f2bf(acc1[2]), f2bf(acc1[3])};
    *(ushort4*)&qs_lds[lr][c] = o0;
    *(ushort4*)&qs_lds[16 + lr][c] = o1;
  } else if (ntg < 48) {  // K/V -> fp8 e4m3, interleaved chunk layout
    bool isK = ntg < 32;
    int c = (isK ? (ntg - 16) : (ntg - 32)) * 16 + lq * 4;
    int pos = ((c >> 3) << 4) + (isK ? 0 : 8) + (c & 7);
    int p0 = __builtin_amdgcn_cvt_pk_fp8_f32(acc0[0], acc0[1], 0, false);
    p0 = __builtin_amdgcn_cvt_pk_fp8_f32(acc0[2], acc0[3], p0, true);
    int p1 = __builtin_amdgcn_cvt_pk_fp8_f32(acc1[0], acc1[1], 0, false);
    p1 = __builtin_amdgcn_cvt_pk_fp8_f32(acc1[2], acc1[3], p1, true);
    *(unsigned*)&kv_lds[lr][pos] = (unsigned)p0;
    *(unsigned*)&kv_lds[16 + lr][pos] = (unsigned)p1;
  } else {  // skip -> bf16 (qs cols 256..319)
    int c = 256 + (ntg - 48) * 16 + lq * 4;
    ushort4 o0{f2bf(acc0[0]), f2bf(acc0[1]), f2bf(acc0[2]), f2bf(acc0[3])};
    ushort4 o1{f2bf(acc1[0]), f2bf(acc1[1]), f2bf(acc1[2]), f2bf(acc1[3])};
    *(ushort4*)&qs_lds[lr][c] = o0;
    *(ushort4*)&qs_lds[16 + lr][c] = o1;
  }
}

template <int K, int AF32>
__global__ __launch_bounds__(256) void gemm_fused(const void* __restrict__ Av, const ushort_t* __restrict__ Wp,
                                                  const float* __restrict__ bias, ushort_t* __restrict__ Cq,
                                                  unsigned char* __restrict__ Ckv, int n) {
  constexpr int KT = K / 32;
  __shared__ ushort_t qs_lds[32][QS_STR];
  __shared__ unsigned char kv_lds[32][KV_STR];
  int tid = threadIdx.x;
  int lane = tid & 63;
  int wv = __builtin_amdgcn_readfirstlane((int)(tid >> 6));
  int m0 = blockIdx.x * 32;
  int lr = lane & 15, lq = lane >> 4;

  bf16x8 a[2][KT];
#pragma unroll
  for (int mr = 0; mr < 2; mr++) {
    int row = m0 + mr * 16 + lr;
    if (row >= n) row = n - 1;
    if constexpr (AF32) {
      const float* Af = (const float*)Av;
#pragma unroll
      for (int kt = 0; kt < KT; kt++) {
        const float* p = Af + (long long)row * K + kt * 32 + lq * 8;
        float4 f0 = *(const float4*)p;
        float4 f1 = *(const float4*)(p + 4);
        u16x8 u;
        u[0] = f2bf(f0.x); u[1] = f2bf(f0.y); u[2] = f2bf(f0.z); u[3] = f2bf(f0.w);
        u[4] = f2bf(f1.x); u[5] = f2bf(f1.y); u[6] = f2bf(f1.z); u[7] = f2bf(f1.w);
        a[mr][kt] = __builtin_bit_cast(bf16x8, u);
      }
    } else {
      const ushort_t* Ab = (const ushort_t*)Av;
#pragma unroll
      for (int kt = 0; kt < KT; kt++)
        a[mr][kt] = *(const bf16x8*)(Ab + (long long)row * K + kt * 32 + lq * 8);
    }
  }
  int ntg0 = wv * 13;
  if constexpr (KT == 2) {
    // depth-3 pipeline: 3 named buffers; compute tile t, prefetch tile t+3
    bf16x8 bwA[2], bwB[2], bwC[2];
    float4 b4A, b4B, b4C;
#pragma unroll
    for (int kt = 0; kt < 2; kt++) {
      bwA[kt] = *(const bf16x8*)(Wp + ((long long)((ntg0 + 0) * 2 + kt) * 64 + lane) * 8);
      bwB[kt] = *(const bf16x8*)(Wp + ((long long)((ntg0 + 1) * 2 + kt) * 64 + lane) * 8);
      bwC[kt] = *(const bf16x8*)(Wp + ((long long)((ntg0 + 2) * 2 + kt) * 64 + lane) * 8);
    }
    b4A = *(const float4*)(bias + (ntg0 + 0) * 16 + lq * 4);
    b4B = *(const float4*)(bias + (ntg0 + 1) * 16 + lq * 4);
    b4C = *(const float4*)(bias + (ntg0 + 2) * 16 + lq * 4);
#pragma unroll 1
    for (int tb = 0; tb < 12; tb += 3) {
      tile_body2(a, bwA, b4A, ntg0 + tb, lr, lq, qs_lds, kv_lds);
      if (tb + 3 < 13) {
#pragma unroll
        for (int kt = 0; kt < 2; kt++)
          bwA[kt] = *(const bf16x8*)(Wp + ((long long)((ntg0 + tb + 3) * 2 + kt) * 64 + lane) * 8);
        b4A = *(const float4*)(bias + (ntg0 + tb + 3) * 16 + lq * 4);
      }
      tile_body2(a, bwB, b4B, ntg0 + tb + 1, lr, lq, qs_lds, kv_lds);
      if (tb + 4 < 13) {
#pragma unroll
        for (int kt = 0; kt < 2; kt++)
          bwB[kt] = *(const bf16x8*)(Wp + ((long long)((ntg0 + tb + 4) * 2 + kt) * 64 + lane) * 8);
        b4B = *(const float4*)(bias + (ntg0 + tb + 4) * 16 + lq * 4);
      }
      tile_body2(a, bwC, b4C, ntg0 + tb + 2, lr, lq, qs_lds, kv_lds);
      if (tb + 5 < 13) {
#pragma unroll
        for (int kt = 0; kt < 2; kt++)
          bwC[kt] = *(const bf16x8*)(Wp + ((long long)((ntg0 + tb + 5) * 2 + kt) * 64 + lane) * 8);
        b4C = *(const float4*)(bias + (ntg0 + tb + 5) * 16 + lq * 4);
      }
    }
    tile_body2(a, bwA, b4A, ntg0 + 12, lr, lq, qs_lds, kv_lds);
  } else {
    // depth-1 named prefetch (layer 0, KT=4) -- identical to verified round-16 path
    bf16x8 bw[KT], bwn[KT];
#pragma unroll
    for (int kt = 0; kt < KT; kt++)
      bw[kt] = *(const bf16x8*)(Wp + ((long long)(ntg0 * KT + kt) * 64 + lane) * 8);
    float4 b4 = *(const float4*)(bias + ntg0 * 16 + lq * 4);
#pragma unroll 1
    for (int t = 0; t < 13; t++) {
      int ntg = ntg0 + t;
      float4 b4n;
      if (t < 12) {
#pragma unroll
        for (int kt = 0; kt < KT; kt++)
          bwn[kt] = *(const bf16x8*)(Wp + ((long long)((ntg + 1) * KT + kt) * 64 + lane) * 8);
        b4n = *(const float4*)(bias + (ntg + 1) * 16 + lq * 4);
      }
      f32x4 acc0 = {b4.x, b4.y, b4.z, b4.w};
      f32x4 acc1 = acc0;
#pragma unroll
      for (int kt = 0; kt < KT; kt++) {
        acc0 = __builtin_amdgcn_mfma_f32_16x16x32_bf16(bw[kt], a[0][kt], acc0, 0, 0, 0);
        acc1 = __builtin_amdgcn_mfma_f32_16x16x32_bf16(bw[kt], a[1][kt], acc1, 0, 0, 0);
      }
      if (ntg < 16) {  // q -> bf16
        int c = ntg * 16 + lq * 4;
        ushort4 o0{f2bf(acc0[0]), f2bf(acc0[1]), f2bf(acc0[2]), f2bf(acc0[3])};
        ushort4 o1{f2bf(acc1[0]), f2bf(acc1[1]), f2bf(acc1[2]), f2bf(acc1[3])};
        *(ushort4*)&qs_lds[lr][c] = o0;
        *(ushort4*)&qs_lds[16 + lr][c] = o1;
      } else if (ntg < 48) {  // K/V -> fp8 e4m3, interleaved chunk layout
        bool isK = ntg < 32;
        int c = (isK ? (ntg - 16) : (ntg - 32)) * 16 + lq * 4;
        int pos = ((c >> 3) << 4) + (isK ? 0 : 8) + (c & 7);
        int p0 = __builtin_amdgcn_cvt_pk_fp8_f32(acc0[0], acc0[1], 0, false);
        p0 = __builtin_amdgcn_cvt_pk_fp8_f32(acc0[2], acc0[3], p0, true);
        int p1 = __builtin_amdgcn_cvt_pk_fp8_f32(acc1[0], acc1[1], 0, false);
        p1 = __builtin_amdgcn_cvt_pk_fp8_f32(acc1[2], acc1[3], p1, true);
        *(unsigned*)&kv_lds[lr][pos] = (unsigned)p0;
        *(unsigned*)&kv_lds[16 + lr][pos] = (unsigned)p1;
      } else {  // skip -> bf16 (qs cols 256..319)
        int c = 256 + (ntg - 48) * 16 + lq * 4;
        ushort4 o0{f2bf(acc0[0]), f2bf(acc0[1]), f2bf(acc0[2]), f2bf(acc0[3])};
        ushort4 o1{f2bf(acc1[0]), f2bf(acc1[1]), f2bf(acc1[2]), f2bf(acc1[3])};
        *(ushort4*)&qs_lds[lr][c] = o0;
        *(ushort4*)&qs_lds[16 + lr][c] = o1;
      }
#pragma unroll
      for (int kt = 0; kt < KT; kt++) bw[kt] = bwn[kt];
      b4 = b4n;
    }
  }
  __syncthreads();
  int rows_here = n - m0;
  if (rows_here > 32) rows_here = 32;
  // qs out: rows are 640B dense -> contiguous 20KB per full block
  const char* qsl = (const char*)qs_lds;
  char* qout = (char*)Cq + (long long)m0 * (QS_ROW * 2);
#pragma unroll 1
  for (int off = tid * 16; off < 32 * 640; off += 4096) {
    int row = off / 640;
    if (row >= rows_here) break;
    int col = off - row * 640;
    uint4 v = *(const uint4*)(qsl + row * (QS_STR * 2) + col);
    *(uint4*)(qout + off) = v;
  }
  // kv out: rows 512B dense -> contiguous 16KB per full block
  const char* kvl = (const char*)kv_lds;
  char* kout = (char*)Ckv + (long long)m0 * KV_ROW;
#pragma unroll 1
  for (int off = tid * 16; off < 32 * 512; off += 4096) {
    int row = off >> 9;
    if (row >= rows_here) break;
    int col = off & 511;
    uint4 v = *(const uint4*)(kvl + row * KV_STR + col);
    *(uint4*)(kout + off) = v;
  }
}

// ---------------- fused attention + head-mean + skip + relu ----------------
// 1 node/wave. lane = half*32 + sl; chunk sl holds K[8ch]|V[8ch] in one 16B load.
// Per iteration: 8 edges (4 per half), packed f32x2 math, defer-max softmax.
__global__ __launch_bounds__(256) void attn_k(const ushort_t* __restrict__ qs,
                                              const unsigned char* __restrict__ kv,
                                              const int* __restrict__ rowp, const int* __restrict__ srt,
                                              ushort_t* __restrict__ hn, int n) {
  int wvv = __builtin_amdgcn_readfirstlane((int)(threadIdx.x >> 6));
  int node = blockIdx.x * 4 + wvv;
  if (node >= n) return;
  int lane = threadIdx.x & 63;
  int half = lane >> 5;
  int sl = lane & 31;
  const uint4 qu = *(const uint4*)(qs + (long long)node * QS_ROW + sl * 8);
  f32x2 qf[4];
  qf[0] = f32x2{blo(qu.x), bhi(qu.x)} * 0.125f;  // 1/sqrt(64) prescaled
  qf[1] = f32x2{blo(qu.y), bhi(qu.y)} * 0.125f;
  qf[2] = f32x2{blo(qu.z), bhi(qu.z)} * 0.125f;
  qf[3] = f32x2{blo(qu.w), bhi(qu.w)} * 0.125f;
  int rs = rowp[node], re = rowp[node + 1];
  int last = re - 1;
  unsigned nm1 = (unsigned)(n - 1);
  float m = -INFINITY, d = 0.f;
  f32x2 a2[4];
#pragma unroll
  for (int j = 0; j < 4; j++) a2[j] = f32x2{0.f, 0.f};

  for (int i = rs; i < re; i += 8) {
    int b0 = i + half * 4;
    // value-clamped indices (srt has >=12B tail slack inside d_ws)
    unsigned i0 = min((unsigned)srt[b0], nm1);
    unsigned i1 = min((unsigned)srt[b0 + 1], nm1);
    unsigned i2 = min((unsigned)srt[b0 + 2], nm1);
    unsigned i3 = min((unsigned)srt[b0 + 3], nm1);
    uint4 u0 = *(const uint4*)(kv + (long long)i0 * KV_ROW + sl * 16);
    uint4 u1 = *(const uint4*)(kv + (long long)i1 * KV_ROW + sl * 16);
    uint4 u2 = *(const uint4*)(kv + (long long)i2 * KV_ROW + sl * 16);
    uint4 u3 = *(const uint4*)(kv + (long long)i3 * KV_ROW + sl * 16);
    f32x2 kf0[4], kf1[4], kf2[4], kf3[4];
    dec8v(u0.x, u0.y, kf0); dec8v(u1.x, u1.y, kf1);
    dec8v(u2.x, u2.y, kf2); dec8v(u3.x, u3.y, kf3);
    f32x2 s0 = qf[0] * kf0[0], s1 = qf[0] * kf1[0], s2 = qf[0] * kf2[0], s3 = qf[0] * kf3[0];
#pragma unroll
    for (int j = 1; j < 4; j++) {
      s0 = s0 + qf[j] * kf0[j];
      s1 = s1 + qf[j] * kf1[j];
      s2 = s2 + qf[j] * kf2[j];
      s3 = s3 + qf[j] * kf3[j];
    }
    float t0 = s0[0] + s0[1], t1 = s1[0] + s1[1], t2 = s2[0] + s2[1], t3 = s3[0] + s3[1];
    t0 += __shfl_xor(t0, 1); t1 += __shfl_xor(t1, 1); t2 += __shfl_xor(t2, 1); t3 += __shfl_xor(t3, 1);
    t0 += __shfl_xor(t0, 2); t1 += __shfl_xor(t1, 2); t2 += __shfl_xor(t2, 2); t3 += __shfl_xor(t3, 2);
    t0 += __shfl_xor(t0, 4); t1 += __shfl_xor(t1, 4); t2 += __shfl_xor(t2, 4); t3 += __shfl_xor(t3, 4);
    if (b0 > last) t0 = -INFINITY;
    if (b0 + 1 > last) t1 = -INFINITY;
    if (b0 + 2 > last) t2 = -INFINITY;
    if (b0 + 3 > last) t3 = -INFINITY;
    float lm = fmaxf(fmaxf(t0, t1), fmaxf(t2, t3));
    lm = fmaxf(lm, __shfl_xor(lm, 32));
    if (__any(lm > m + 8.f)) {  // defer-max: rescale only on significant growth
      float mn = fmaxf(m, lm);
      float co = __expf(m - mn);  // first iter: exp(-inf)=0
      d *= co;
#pragma unroll
      for (int j = 0; j < 4; j++) a2[j] = a2[j] * co;
      m = mn;
    }
    float p0e = __expf(t0 - m), p1e = __expf(t1 - m), p2e = __expf(t2 - m), p3e = __expf(t3 - m);
    d += (p0e + p1e) + (p2e + p3e);
    f32x2 vf0[4], vf1[4], vf2[4], vf3[4];
    dec8v(u0.z, u0.w, vf0); dec8v(u1.z, u1.w, vf1);
    dec8v(u2.z, u2.w, vf2); dec8v(u3.z, u3.w, vf3);
    f32x2 pe0 = {p0e, p0e}, pe1 = {p1e, p1e}, pe2 = {p2e, p2e}, pe3 = {p3e, p3e};
#pragma unroll
    for (int j = 0; j < 4; j++)
      a2[j] = a2[j] + (pe0 * vf0[j] + pe1 * vf1[j]) + (pe2 * vf2[j] + pe3 * vf3[j]);
  }
  // merge halves (same chunk at lane^32)
  d += __shfl_xor(d, 32);
  float a[8];
#pragma unroll
  for (int j = 0; j < 4; j++) {
    a[2 * j] = a2[j][0] + __shfl_xor(a2[j][0], 32);
    a[2 * j + 1] = a2[j][1] + __shfl_xor(a2[j][1], 32);
  }
  float inv = (d > 0.f) ? 1.f / d : 0.f;
  float r[8];
#pragma unroll
  for (int j = 0; j < 8; j++) {
    r[j] = a[j] * inv;
    r[j] += __shfl_xor(r[j], 8);   // head ^1
    r[j] += __shfl_xor(r[j], 16);  // head ^2
  }
  if (lane < 8) {
    const u16x8 s8 = *(const u16x8*)(qs + (long long)node * QS_ROW + 256 + lane * 8);
    u16x8 o;
#pragma unroll
    for (int j = 0; j < 8; j++)
      o[j] = f2bf(fmaxf(r[j] * 0.25f + bf2f(s8[j]), 0.f));
    *(u16x8*)(hn + (long long)node * HID + lane * 8) = o;
  }
}

// ---------------- global add pool (run-length; batch is sorted) ----------------
#define POOL_NPB 128
__global__ __launch_bounds__(64) void pool_k(const ushort_t* __restrict__ h, const int* __restrict__ batch,
                                             float* __restrict__ out, int n) {
  int c = threadIdx.x;
  int n0 = blockIdx.x * POOL_NPB;
  int n1 = n0 + POOL_NPB;
  if (n1 > n) n1 = n;
  if (n0 >= n) return;
  float acc = 0.f;
  int g = batch[n0];
  for (int node = n0; node < n1; node++) {
    int gb = batch[node];
    if (gb != g) {
      atomicAdd(&out[g * 64 + c], acc);
      acc = 0.f;
      g = gb;
    }
    acc += bf2f(h[(long long)node * 64 + c]);
  }
  atomicAdd(&out[g * 64 + c], acc);
}

extern "C" void kernel_launch(void* const* d_in, const int* in_sizes, int n_in,
                              void* d_out, int out_size, void* d_ws, size_t ws_size,
                              hipStream_t stream) {
  const float* x  = (const float*)d_in[0];
  const int* ei   = (const int*)d_in[1];
  const int* batch = (const int*)d_in[2];
  const float* w0 = (const float*)d_in[3];
  const float* b0 = (const float*)d_in[4];
  const float* Wq = (const float*)d_in[5];
  const float* bq = (const float*)d_in[6];
  const float* Wk = (const float*)d_in[7];
  const float* bk = (const float*)d_in[8];
  const float* Wv = (const float*)d_in[9];
  const float* bv = (const float*)d_in[10];
  const float* Ws = (const float*)d_in[11];
  const float* bs = (const float*)d_in[12];
  int N = in_sizes[0] / F_IN;
  int E = in_sizes[1] / 2;
  const int* esrc = ei;
  const int* edst = ei + E;

  // ---- workspace layout ----
  float* bp = (float*)d_ws;                                   // 3*832 f32
  unsigned char* kvb = (unsigned char*)(bp + 3 * QSW);        // N*512 fp8
  ushort_t* ha = (ushort_t*)(kvb + (size_t)N * KV_ROW);
  ushort_t* hb = ha + (long long)N * HID;
  ushort_t* qs = hb + (long long)N * HID;                     // N x 320 bf16
  ushort_t* wp0  = qs + (long long)N * QS_ROW;                // 208 * 512
  ushort_t* wp12 = wp0 + 208 * 512;                           // 2 * 104 * 512
  int* cnt  = (int*)(wp12 + 2 * 104 * 512);
  int* excl = cnt + N;
  int* rowp = excl + N;
  int* bsum = rowp + N + 1;
  int* rank = bsum + 64;                                      // E ints
  int* srt  = rank + E;                                       // E ints (+tail slack in ws)

  int nbE = (E + 255) / 256;
  int sbBlocks = (N + 1023) / 1024;

  // CSR by dst
  hipMemsetAsync(cnt, 0, (size_t)N * sizeof(int), stream);
  hist_rank_k<<<nbE, 256, 0, stream>>>(edst, cnt, rank, E);
  scan_block_k<<<sbBlocks, 1024, 0, stream>>>(cnt, excl, bsum, N);
  scatter_rowptr_k<<<nbE, 256, 0, stream>>>(esrc, edst, excl, bsum, rank, rowp, srt, N, E, sbBlocks);

  // weight packing + lin0 composition
  pack2_k<<<419, 256, 0, stream>>>(Wq, Wk, Wv, Ws, w0, b0, bq, bk, bv, bs, wp0, wp12, bp);

  int gBlocks = (N + 31) / 32;  // 1 block = 32 rows x 832 cols (LDS 37.9KB)

  // layer 0: composed weights, A = x fp32 direct (K=128)
  gemm_fused<128, 1><<<gBlocks, 256, 0, stream>>>(x, wp0, bp, qs, kvb, N);
  attn_k<<<(N + 3) / 4, 256, 0, stream>>>(qs, kvb, rowp, srt, ha, N);
  // layer 1
  gemm_fused<64, 0><<<gBlocks, 256, 0, stream>>>(ha, wp12, bp + QSW, qs, kvb, N);
  attn_k<<<(N + 3) / 4, 256, 0, stream>>>(qs, kvb, rowp, srt, hb, N);
  // layer 2
  gemm_fused<64, 0><<<gBlocks, 256, 0, stream>>>(hb, wp12 + 104 * 512, bp + 2 * QSW, qs, kvb, N);
  attn_k<<<(N + 3) / 4, 256, 0, stream>>>(qs, kvb, rowp, srt, ha, N);

  hipMemsetAsync(d_out, 0, (size_t)out_size * sizeof(float), stream);
  pool_k<<<(N + POOL_NPB - 1) / POOL_NPB, 64, 0, stream>>>(ha, batch, (float*)d_out, N);
}